// Round 8
// baseline (1623.340 us; speedup 1.0000x reference)
//
#include <hip/hip_runtime.h>
#include <cstdint>
#include <cstddef>

typedef unsigned long long u64;

#define NB 16
#define NC 64
#define NN 4096
#define NM 1024
#define NK 32

// ---------- DPP wave-reduction helpers (row_shr 1/2/4/8 + row_bcast 15/31) ----------

template <int C>
__device__ __forceinline__ float dppf(float x, float ident) {
  return __int_as_float(__builtin_amdgcn_update_dpp(
      __float_as_int(ident), __float_as_int(x), C, 0xf, 0xf, false));
}

template <int C>
__device__ __forceinline__ unsigned dppu(unsigned x, unsigned ident) {
  return (unsigned)__builtin_amdgcn_update_dpp(
      (int)ident, (int)x, C, 0xf, 0xf, false);
}

// full-wave (64-lane) float max; result broadcast via readlane(63)
__device__ __forceinline__ float wave_fmax(float x) {
  const float I = __int_as_float(0xff800000);  // -inf
  x = fmaxf(x, dppf<0x111>(x, I));
  x = fmaxf(x, dppf<0x112>(x, I));
  x = fmaxf(x, dppf<0x114>(x, I));
  x = fmaxf(x, dppf<0x118>(x, I));
  x = fmaxf(x, dppf<0x142>(x, I));  // row_bcast:15
  x = fmaxf(x, dppf<0x143>(x, I));  // row_bcast:31
  return __int_as_float(__builtin_amdgcn_readlane(__float_as_int(x), 63));
}

__device__ __forceinline__ float wave_fmin(float x) {
  const float I = __int_as_float(0x7f800000);  // +inf
  x = fminf(x, dppf<0x111>(x, I));
  x = fminf(x, dppf<0x112>(x, I));
  x = fminf(x, dppf<0x114>(x, I));
  x = fminf(x, dppf<0x118>(x, I));
  x = fminf(x, dppf<0x142>(x, I));
  x = fminf(x, dppf<0x143>(x, I));
  return __int_as_float(__builtin_amdgcn_readlane(__float_as_int(x), 63));
}

__device__ __forceinline__ unsigned wave_umin(unsigned x) {
  const unsigned I = 0xFFFFFFFFu;
  unsigned t;
  t = dppu<0x111>(x, I); x = x < t ? x : t;
  t = dppu<0x112>(x, I); x = x < t ? x : t;
  t = dppu<0x114>(x, I); x = x < t ? x : t;
  t = dppu<0x118>(x, I); x = x < t ? x : t;
  t = dppu<0x142>(x, I); x = x < t ? x : t;
  t = dppu<0x143>(x, I); x = x < t ? x : t;
  return (unsigned)__builtin_amdgcn_readlane((int)x, 63);
}

// ---------- kernel 0: pad W1 (64x67) -> W1p (64x68, zero col 67) ----------

__global__ __launch_bounds__(256) void pad_w1(const float* __restrict__ W1,
                                              float* __restrict__ W1p) {
  int g = blockIdx.x * 256 + threadIdx.x;
  if (g >= 64 * 68) return;
  int o = g / 68, c = g - o * 68;
  W1p[g] = (c < 67) ? W1[o * 67 + c] : 0.0f;
}

// ---------- kernel 1: feat (b,c,n) -> featT (b,n,c) ----------

__global__ __launch_bounds__(256) void transpose_feat(const float* __restrict__ feat,
                                                      float* __restrict__ featT) {
  int g = blockIdx.x * 256 + threadIdx.x;     // < NB*NN*NC
  int c = g & 63;
  int n = (g >> 6) & 4095;
  int b = g >> 18;
  featT[g] = feat[((size_t)(b * NC + c)) * NN + n];
}

// ---------- kernel 2: farthest point sampling (R4 version, verbatim) ----------

__global__ __launch_bounds__(256) void fps_kernel(const float* __restrict__ loc,
                                                  float* __restrict__ out_setloc) {
  __shared__ float4 red[2][4];
  const int b = blockIdx.x;
  const int tid = threadIdx.x;
  const int lane = tid & 63, wid = tid >> 6;
  const float* Lx = loc + (size_t)b * 3 * NN;
  const float* Ly = Lx + NN;
  const float* Lz = Ly + NN;
  const int p0 = tid * 16;
  float px[16], py[16], pz[16], dist[16];
#pragma unroll
  for (int j4 = 0; j4 < 4; ++j4) {
    float4 vx = *(const float4*)(Lx + p0 + 4 * j4);
    float4 vy = *(const float4*)(Ly + p0 + 4 * j4);
    float4 vz = *(const float4*)(Lz + p0 + 4 * j4);
    px[4 * j4] = vx.x; px[4 * j4 + 1] = vx.y; px[4 * j4 + 2] = vx.z; px[4 * j4 + 3] = vx.w;
    py[4 * j4] = vy.x; py[4 * j4 + 1] = vy.y; py[4 * j4 + 2] = vy.z; py[4 * j4 + 3] = vy.w;
    pz[4 * j4] = vz.x; pz[4 * j4 + 1] = vz.y; pz[4 * j4 + 2] = vz.z; pz[4 * j4 + 3] = vz.w;
  }
#pragma unroll
  for (int j = 0; j < 16; ++j) dist[j] = __int_as_float(0x7f800000);
  if (tid == 0) red[1][0] = make_float4(0.0f, px[0], py[0], pz[0]);  // bootstrap: point 0
  __syncthreads();
  float4 boot = red[1][0];
  float sx = boot.y, sy = boot.z, sz = boot.w;

  // register shift-queue of captured winners (slot s captured by tid == s%256)
  float w0x = 0, w0y = 0, w0z = 0, w1x = 0, w1y = 0, w1z = 0;
  float w2x = 0, w2y = 0, w2z = 0, w3x = 0, w3y = 0, w3z = 0;
  if (tid == 0) { w0x = sx; w0y = sy; w0z = sz; }  // slot 0 = point 0

  for (int s = 0; s < NM - 1; ++s) {  // compute winners for slots 1..1023
    float bd = -1.0f, bx = 0.0f, by = 0.0f, bz = 0.0f;
#pragma unroll
    for (int j = 0; j < 16; ++j) {
      // match numpy: plain mul, left-assoc adds, no contraction
      float dx = __fsub_rn(px[j], sx);
      float dy = __fsub_rn(py[j], sy);
      float dz = __fsub_rn(pz[j], sz);
      float d2 = __fadd_rn(__fadd_rn(__fmul_rn(dx, dx), __fmul_rn(dy, dy)), __fmul_rn(dz, dz));
      float nd = fminf(dist[j], d2);
      dist[j] = nd;
      bool g = nd > bd;  // strict > keeps lowest j (= lowest index)
      bd = g ? nd : bd;
      bx = g ? px[j] : bx;
      by = g ? py[j] : by;
      bz = g ? pz[j] : bz;
    }
    // wave argmax: DPP value max, lowest tied lane (= lowest index) writes cand
    float wmax = wave_fmax(bd);
    u64 m = __ballot(bd == wmax);
    if (lane == __ffsll((long long)m) - 1) red[s & 1][wid] = make_float4(bd, bx, by, bz);
    __syncthreads();
    // 4-way serial argmax, ascending wid + strict > == global first-max
    float4 c0 = red[s & 1][0], c1 = red[s & 1][1], c2 = red[s & 1][2], c3 = red[s & 1][3];
    float bdd = c0.x; sx = c0.y; sy = c0.z; sz = c0.w;
    bool g1 = c1.x > bdd; bdd = g1 ? c1.x : bdd; sx = g1 ? c1.y : sx; sy = g1 ? c1.z : sy; sz = g1 ? c1.w : sz;
    bool g2 = c2.x > bdd; bdd = g2 ? c2.x : bdd; sx = g2 ? c2.y : sx; sy = g2 ? c2.z : sy; sz = g2 ? c2.w : sz;
    bool g3 = c3.x > bdd; bdd = g3 ? c3.x : bdd; sx = g3 ? c3.y : sx; sy = g3 ? c3.z : sy; sz = g3 ? c3.w : sz;
    // capture slot s+1 into the shift queue (static indices only)
    if (tid == ((s + 1) & 255)) {
      w3x = w2x; w3y = w2y; w3z = w2z;
      w2x = w1x; w2y = w1y; w2z = w1z;
      w1x = w0x; w1y = w0y; w1z = w0z;
      w0x = sx;  w0y = sy;  w0z = sz;
    }
  }
  // thread t holds slots t(w3), t+256(w2), t+512(w1), t+768(w0); coalesced write
  float* Ox = out_setloc + (b * 3 + 0) * NM;
  float* Oy = out_setloc + (b * 3 + 1) * NM;
  float* Oz = out_setloc + (b * 3 + 2) * NM;
  Ox[tid] = w3x;       Oy[tid] = w3y;       Oz[tid] = w3z;
  Ox[tid + 256] = w2x; Oy[tid + 256] = w2y; Oz[tid + 256] = w2z;
  Ox[tid + 512] = w1x; Oy[tid + 512] = w1y; Oz[tid + 512] = w1z;
  Ox[tid + 768] = w0x; Oy[tid + 768] = w0y; Oz[tid + 768] = w0z;
}

// ---------- kernel 3: kNN (one wave per query, DPP-min extraction) ----------

__global__ __launch_bounds__(256) void knn_kernel(const float* __restrict__ loc,
                                                  const float* __restrict__ setloc,
                                                  int* __restrict__ ws_knn) {
  const int wq = blockIdx.x * 4 + (threadIdx.x >> 6);  // query id, < NB*NM
  const int lane = threadIdx.x & 63;
  const int b = wq >> 10, mq = wq & 1023;
  const float* Sb = setloc + (size_t)b * 3 * NM;
  float xs = Sb[mq], ys = Sb[NM + mq], zs = Sb[2 * NM + mq];
  float sqs = __fadd_rn(__fadd_rn(__fmul_rn(xs, xs), __fmul_rn(ys, ys)), __fmul_rn(zs, zs));
  const float* Lx = loc + (size_t)b * 3 * NN;
  const float* Ly = Lx + NN;
  const float* Lz = Ly + NN;
  const float INF = __int_as_float(0x7f800000);

  // per-lane two smallest (value, index); lane owns points p = j*64+lane
  float k1 = INF, k2 = INF;
  unsigned i1 = 0xFFFFFFFFu, i2 = 0xFFFFFFFFu;
#pragma unroll 8
  for (int j = 0; j < 64; ++j) {
    int p = j * 64 + lane;
    float x = Lx[p], y = Ly[p], z = Lz[p];
    float sql = __fadd_rn(__fadd_rn(__fmul_rn(x, x), __fmul_rn(y, y)), __fmul_rn(z, z));
    float cr  = __fadd_rn(__fadd_rn(__fmul_rn(xs, x), __fmul_rn(ys, y)), __fmul_rn(zs, z));
    float d2  = __fsub_rn(__fadd_rn(sqs, sql), __fmul_rn(2.0f, cr));
    if (d2 < k1)      { k2 = k1; i2 = i1; k1 = d2; i1 = (unsigned)p; }
    else if (d2 < k2) { k2 = d2; i2 = (unsigned)p; }
  }

  u64 used = 0;        // per-lane mask of extracted j-slots
  unsigned keep = 0;   // lane s holds round-s winner
  for (int s = 0; s < NK; ++s) {
    float wmin = wave_fmin(k1);
    u64 mask = __ballot(k1 == wmin);
    int ownerLane;
    if (__popcll(mask) > 1) {
      // exact tie-break: smallest global index among tied lanes
      unsigned cand = (k1 == wmin) ? i1 : 0xFFFFFFFFu;
      unsigned minp = wave_umin(cand);
      u64 m2 = __ballot(k1 == wmin && i1 == minp);
      ownerLane = __ffsll((long long)m2) - 1;
    } else {
      ownerLane = __ffsll((long long)mask) - 1;
    }
    unsigned widx = (unsigned)__builtin_amdgcn_readlane((int)i1, ownerLane);
    if (lane == s) keep = widx;
    if (lane == ownerLane) {
      used |= 1ull << (i1 >> 6);
      k1 = k2; i1 = i2;
      k2 = INF; i2 = 0xFFFFFFFFu;
      if (__float_as_uint(k1) == 0x7f800000u) {
        // rare refill: recompute this lane's remaining distances (L2-hot loc)
#pragma unroll 8
        for (int j = 0; j < 64; ++j) {
          if (!((used >> j) & 1ull)) {
            int p = j * 64 + lane;
            float x = Lx[p], y = Ly[p], z = Lz[p];
            float sql = __fadd_rn(__fadd_rn(__fmul_rn(x, x), __fmul_rn(y, y)), __fmul_rn(z, z));
            float cr  = __fadd_rn(__fadd_rn(__fmul_rn(xs, x), __fmul_rn(ys, y)), __fmul_rn(zs, z));
            float d2  = __fsub_rn(__fadd_rn(sqs, sql), __fmul_rn(2.0f, cr));
            if (d2 < k1)      { k2 = k1; i2 = i1; k1 = d2; i1 = (unsigned)p; }
            else if (d2 < k2) { k2 = d2; i2 = (unsigned)p; }
          }
        }
      }
    }
  }
  if (lane < NK) ws_knn[(size_t)wq * NK + lane] = (int)keep;
}

// ---------- kernel 4: fused gather + 3-layer MLP + maxpool ----------
// TWO COLUMNS PER THREAD: wave = 4 queries x 16 lanes; lane handles neighbor
// cols lane16 and lane16+16. Halves the per-CU ds_read_b128 count (the LDS
// pipe was the measured bottleneck: 32 waves/CU x 4160 reads x ~13cyc = 720us).
// Per chunk: 8 LDS reads feed 64 FMAs (was 32). ~320 VGPR -> 1 wave/SIMD.

#define LD4(p) (*(const float4*)(p))
// one weight row (float4 W) into two columns' accumulators
#define R2(W, AA, CC) { \
    AA = fmaf(W.x, xa0, AA); AA = fmaf(W.y, xa1, AA); \
    AA = fmaf(W.z, xa2, AA); AA = fmaf(W.w, xa3, AA); \
    CC = fmaf(W.x, xb0, CC); CC = fmaf(W.y, xb1, CC); \
    CC = fmaf(W.z, xb2, CC); CC = fmaf(W.w, xb3, CC); }
// 4 input channels x 8 output rows x 2 columns
#define CHK2(XS, YS, S) { \
    float xa0 = XS[4*ch], xa1 = XS[4*ch+1], xa2 = XS[4*ch+2], xa3 = XS[4*ch+3]; \
    float xb0 = YS[4*ch], xb1 = YS[4*ch+1], xb2 = YS[4*ch+2], xb3 = YS[4*ch+3]; \
    float4 q0 = LD4(wr+0*(S)+4*ch), q1 = LD4(wr+1*(S)+4*ch); \
    float4 q2 = LD4(wr+2*(S)+4*ch), q3 = LD4(wr+3*(S)+4*ch); \
    float4 q4 = LD4(wr+4*(S)+4*ch), q5 = LD4(wr+5*(S)+4*ch); \
    float4 q6 = LD4(wr+6*(S)+4*ch), q7 = LD4(wr+7*(S)+4*ch); \
    R2(q0,a0,c0) R2(q1,a1,c1) R2(q2,a2,c2) R2(q3,a3,c3) \
    R2(q4,a4,c4) R2(q5,a5,c5) R2(q6,a6,c6) R2(q7,a7,c7) }
#define RELU16() { \
    a0=fmaxf(a0,0.f); a1=fmaxf(a1,0.f); a2=fmaxf(a2,0.f); a3=fmaxf(a3,0.f); \
    a4=fmaxf(a4,0.f); a5=fmaxf(a5,0.f); a6=fmaxf(a6,0.f); a7=fmaxf(a7,0.f); \
    c0=fmaxf(c0,0.f); c1=fmaxf(c1,0.f); c2=fmaxf(c2,0.f); c3=fmaxf(c3,0.f); \
    c4=fmaxf(c4,0.f); c5=fmaxf(c5,0.f); c6=fmaxf(c6,0.f); c7=fmaxf(c7,0.f); }
#define SCROW2(YA, YB, base) { \
    YA[base]=a0; YA[base+1]=a1; YA[base+2]=a2; YA[base+3]=a3; \
    YA[base+4]=a4; YA[base+5]=a5; YA[base+6]=a6; YA[base+7]=a7; \
    YB[base]=c0; YB[base+1]=c1; YB[base+2]=c2; YB[base+3]=c3; \
    YB[base+4]=c4; YB[base+5]=c5; YB[base+6]=c6; YB[base+7]=c7; }
#define SCAT2(YA, YB) switch (ob) { \
    case 0: SCROW2(YA, YB, 0) break;  case 1: SCROW2(YA, YB, 8) break; \
    case 2: SCROW2(YA, YB, 16) break; case 3: SCROW2(YA, YB, 24) break; \
    case 4: SCROW2(YA, YB, 32) break; case 5: SCROW2(YA, YB, 40) break; \
    case 6: SCROW2(YA, YB, 48) break; case 7: SCROW2(YA, YB, 56) break; }
// maxpool butterfly across the 16-lane group (cols already paired per-thread)
#define BF16G(a) { a = fmaxf(a, __shfl_xor(a, 8, 64)); a = fmaxf(a, __shfl_xor(a, 4, 64)); \
                   a = fmaxf(a, __shfl_xor(a, 2, 64)); a = fmaxf(a, __shfl_xor(a, 1, 64)); }
#define STAGE(DST4, SRC4, N4) { \
    for (int t = threadIdx.x; t < (N4); t += 256) \
      ((float4*)(DST4))[t] = ((const float4*)(SRC4))[t]; }

__global__ __launch_bounds__(256, 1) void mlp_kernel(
    const float* __restrict__ featT, const float* __restrict__ loc,
    const float* __restrict__ setloc, const int* __restrict__ ws_knn,
    const float* __restrict__ W1p, const float* __restrict__ b1,
    const float* __restrict__ W2, const float* __restrict__ b2,
    const float* __restrict__ W3, const float* __restrict__ b3,
    float* __restrict__ out) {
  __shared__ __align__(16) float wlds[8192];  // 32KB: max(W1p 4352, W2 4096, W3 8192)
  const int tid = threadIdx.x;
  const int lane16 = tid & 15;
  const int q = (blockIdx.x * 256 + tid) >> 4;  // query id, < 16384
  const int b = q >> 10, mq = q & 1023;
  const int nk0 = ws_knn[(size_t)q * NK + lane16];
  const int nk1 = ws_knn[(size_t)q * NK + lane16 + 16];

  // gather the two input columns: 64 feat channels + 3 rel-loc + zero pad
  const float* fx0 = featT + ((size_t)(b * NN + nk0)) * 64;
  const float* fx1 = featT + ((size_t)(b * NN + nk1)) * 64;
  float xA[68], xB[68];
#pragma unroll
  for (int i = 0; i < 16; ++i) {
    float4 v = LD4(fx0 + 4 * i);
    xA[4*i] = v.x; xA[4*i+1] = v.y; xA[4*i+2] = v.z; xA[4*i+3] = v.w;
    float4 w = LD4(fx1 + 4 * i);
    xB[4*i] = w.x; xB[4*i+1] = w.y; xB[4*i+2] = w.z; xB[4*i+3] = w.w;
  }
  {
    const float* Lb = loc + (size_t)b * 3 * NN;
    const float* Sb = setloc + (size_t)b * 3 * NM;
    float s0 = Sb[mq], s1 = Sb[NM + mq], s2 = Sb[2 * NM + mq];
    xA[64] = Lb[nk0] - s0;
    xA[65] = Lb[NN + nk0] - s1;
    xA[66] = Lb[2 * NN + nk0] - s2;
    xA[67] = 0.0f;
    xB[64] = Lb[nk1] - s0;
    xB[65] = Lb[NN + nk1] - s1;
    xB[66] = Lb[2 * NN + nk1] - s2;
    xB[67] = 0.0f;
  }

  // ---- layer 1: 68 -> 64 (padded), weights in LDS ----
  STAGE(wlds, W1p, 1088)   // 4352 f32
  __syncthreads();
  float yA[64], yB[64];
#pragma unroll 1
  for (int ob = 0; ob < 8; ++ob) {
    const float* wr = wlds + ob * 544;
    const float* bb = b1 + ob * 8;
    float a0 = bb[0], a1 = bb[1], a2 = bb[2], a3 = bb[3];
    float a4 = bb[4], a5 = bb[5], a6 = bb[6], a7 = bb[7];
    float c0 = a0, c1 = a1, c2 = a2, c3 = a3;
    float c4 = a4, c5 = a5, c6 = a6, c7 = a7;
#pragma unroll
    for (int ch = 0; ch < 17; ++ch) CHK2(xA, xB, 68)
    RELU16();
    SCAT2(yA, yB);
  }
  __syncthreads();

  // ---- layer 2: 64 -> 64 ----
  STAGE(wlds, W2, 1024)    // 4096 f32
  __syncthreads();
  float zA[64], zB[64];
#pragma unroll 1
  for (int ob = 0; ob < 8; ++ob) {
    const float* wr = wlds + ob * 512;
    const float* bb = b2 + ob * 8;
    float a0 = bb[0], a1 = bb[1], a2 = bb[2], a3 = bb[3];
    float a4 = bb[4], a5 = bb[5], a6 = bb[6], a7 = bb[7];
    float c0 = a0, c1 = a1, c2 = a2, c3 = a3;
    float c4 = a4, c5 = a5, c6 = a6, c7 = a7;
#pragma unroll
    for (int ch = 0; ch < 16; ++ch) CHK2(yA, yB, 64)
    RELU16();
    SCAT2(zA, zB);
  }
  __syncthreads();

  // ---- layer 3: 64 -> 128, fused maxpool (pair + 16-lane butterfly) + store ----
  STAGE(wlds, W3, 2048)    // 8192 f32
  __syncthreads();
#pragma unroll 1
  for (int ob = 0; ob < 16; ++ob) {
    const float* wr = wlds + ob * 512;
    const float* bb = b3 + ob * 8;
    float a0 = bb[0], a1 = bb[1], a2 = bb[2], a3 = bb[3];
    float a4 = bb[4], a5 = bb[5], a6 = bb[6], a7 = bb[7];
    float c0 = a0, c1 = a1, c2 = a2, c3 = a3;
    float c4 = a4, c5 = a5, c6 = a6, c7 = a7;
#pragma unroll
    for (int ch = 0; ch < 16; ++ch) CHK2(zA, zB, 64)
    RELU16();
    float m0 = fmaxf(a0, c0), m1 = fmaxf(a1, c1), m2 = fmaxf(a2, c2), m3 = fmaxf(a3, c3);
    float m4 = fmaxf(a4, c4), m5 = fmaxf(a5, c5), m6 = fmaxf(a6, c6), m7 = fmaxf(a7, c7);
    BF16G(m0); BF16G(m1); BF16G(m2); BF16G(m3);
    BF16G(m4); BF16G(m5); BF16G(m6); BF16G(m7);
    if (lane16 == 0) {
      float* op = out + ((size_t)b * 128 + ob * 8) * NM + mq;
      op[0] = m0;       op[NM] = m1;     op[2 * NM] = m2; op[3 * NM] = m3;
      op[4 * NM] = m4;  op[5 * NM] = m5; op[6 * NM] = m6; op[7 * NM] = m7;
    }
  }
}

// ---------- launch ----------

extern "C" void kernel_launch(void* const* d_in, const int* in_sizes, int n_in,
                              void* d_out, int out_size, void* d_ws, size_t ws_size,
                              hipStream_t stream) {
  (void)in_sizes; (void)n_in; (void)out_size; (void)ws_size;
  const float* feat = (const float*)d_in[0];
  const float* loc  = (const float*)d_in[1];
  const float* W1   = (const float*)d_in[2];
  const float* b1   = (const float*)d_in[3];
  const float* W2   = (const float*)d_in[4];
  const float* b2   = (const float*)d_in[5];
  const float* W3   = (const float*)d_in[6];
  const float* b3   = (const float*)d_in[7];
  float* out = (float*)d_out;

  char* ws = (char*)d_ws;
  int*   ws_knn   = (int*)ws;                           // 16*1024*32 i32 = 2 MB
  float* ws_featT = (float*)(ws + 2097152);             // 16*4096*64 f32 = 16.75 MB
  float* ws_w1p   = (float*)(ws + 2097152 + 16777216);  // 64*68 f32

  float* out_setfeat = out;                          // (16,128,1024)
  float* out_setloc  = out + (size_t)NB * 128 * NM;  // (16,3,1024)

  pad_w1<<<dim3(17), dim3(256), 0, stream>>>(W1, ws_w1p);
  transpose_feat<<<dim3((NB * NN * NC) / 256), dim3(256), 0, stream>>>(feat, ws_featT);
  fps_kernel<<<dim3(NB), dim3(256), 0, stream>>>(loc, out_setloc);
  knn_kernel<<<dim3((NB * NM) / 4), dim3(256), 0, stream>>>(loc, out_setloc, ws_knn);
  mlp_kernel<<<dim3((NB * NM) * 16 / 256), dim3(256), 0, stream>>>(
      ws_featT, loc, out_setloc, ws_knn, ws_w1p, b1, W2, b2, W3, b3, out_setfeat);
}

// Round 9
// 1284.969 us; speedup vs baseline: 1.2633x; 1.2633x over previous
//
#include <hip/hip_runtime.h>
#include <cstdint>
#include <cstddef>

typedef unsigned long long u64;
typedef __attribute__((ext_vector_type(8))) short bf16x8;
typedef __attribute__((ext_vector_type(4))) float f32x4;

#define NB 16
#define NC 64
#define NN 4096
#define NM 1024
#define NK 32
#define KP1 104
#define KP2 72

// ---------- DPP wave-reduction helpers ----------

template <int C>
__device__ __forceinline__ float dppf(float x, float ident) {
  return __int_as_float(__builtin_amdgcn_update_dpp(
      __float_as_int(ident), __float_as_int(x), C, 0xf, 0xf, false));
}

template <int C>
__device__ __forceinline__ unsigned dppu(unsigned x, unsigned ident) {
  return (unsigned)__builtin_amdgcn_update_dpp(
      (int)ident, (int)x, C, 0xf, 0xf, false);
}

__device__ __forceinline__ float wave_fmax(float x) {
  const float I = __int_as_float(0xff800000);  // -inf
  x = fmaxf(x, dppf<0x111>(x, I));
  x = fmaxf(x, dppf<0x112>(x, I));
  x = fmaxf(x, dppf<0x114>(x, I));
  x = fmaxf(x, dppf<0x118>(x, I));
  x = fmaxf(x, dppf<0x142>(x, I));  // row_bcast:15
  x = fmaxf(x, dppf<0x143>(x, I));  // row_bcast:31
  return __int_as_float(__builtin_amdgcn_readlane(__float_as_int(x), 63));
}

__device__ __forceinline__ float wave_fmin(float x) {
  const float I = __int_as_float(0x7f800000);  // +inf
  x = fminf(x, dppf<0x111>(x, I));
  x = fminf(x, dppf<0x112>(x, I));
  x = fminf(x, dppf<0x114>(x, I));
  x = fminf(x, dppf<0x118>(x, I));
  x = fminf(x, dppf<0x142>(x, I));
  x = fminf(x, dppf<0x143>(x, I));
  return __int_as_float(__builtin_amdgcn_readlane(__float_as_int(x), 63));
}

__device__ __forceinline__ unsigned wave_umin(unsigned x) {
  const unsigned I = 0xFFFFFFFFu;
  unsigned t;
  t = dppu<0x111>(x, I); x = x < t ? x : t;
  t = dppu<0x112>(x, I); x = x < t ? x : t;
  t = dppu<0x114>(x, I); x = x < t ? x : t;
  t = dppu<0x118>(x, I); x = x < t ? x : t;
  t = dppu<0x142>(x, I); x = x < t ? x : t;
  t = dppu<0x143>(x, I); x = x < t ? x : t;
  return (unsigned)__builtin_amdgcn_readlane((int)x, 63);
}

// max over 16-lane group via DPP row_ror 8/4/2/1
#define RED16(m) { m = fmaxf(m, dppf<0x128>(m, 0.f)); m = fmaxf(m, dppf<0x124>(m, 0.f)); \
                   m = fmaxf(m, dppf<0x122>(m, 0.f)); m = fmaxf(m, dppf<0x121>(m, 0.f)); }

// f32 -> bf16 (RNE), and pack pair into u32
__device__ __forceinline__ unsigned short f2bf(float f) {
  unsigned u = __float_as_uint(f);
  return (unsigned short)((u + 0x7FFFu + ((u >> 16) & 1u)) >> 16);
}
__device__ __forceinline__ int pk(float a, float b) {
  return (int)f2bf(a) | ((int)f2bf(b) << 16);
}

// ---------- kernel 0: weights f32 -> padded bf16 tiles ----------
// w1b [64][KP1] (k>=67 zero), w2b [64][KP2] (k>=64 zero), w3b [128][KP2]

__global__ __launch_bounds__(256) void w_prep(
    const float* __restrict__ W1, const float* __restrict__ W2,
    const float* __restrict__ W3, short* __restrict__ w1b,
    short* __restrict__ w2b, short* __restrict__ w3b) {
  int gg = blockIdx.x * 256 + threadIdx.x;
  if (gg < 64 * KP1) {
    int r = gg / KP1, k = gg - r * KP1;
    w1b[gg] = (k < 67) ? (short)f2bf(W1[r * 67 + k]) : (short)0;
  } else if (gg < 64 * KP1 + 64 * KP2) {
    int g2 = gg - 64 * KP1;
    int r = g2 / KP2, k = g2 - r * KP2;
    w2b[g2] = (k < 64) ? (short)f2bf(W2[r * 64 + k]) : (short)0;
  } else if (gg < 64 * KP1 + 64 * KP2 + 128 * KP2) {
    int g3 = gg - 64 * KP1 - 64 * KP2;
    int r = g3 / KP2, k = g3 - r * KP2;
    w3b[g3] = (k < 64) ? (short)f2bf(W3[r * 64 + k]) : (short)0;
  }
}

// ---------- kernel 1: feat (b,c,n) -> featT (b,n,c) ----------

__global__ __launch_bounds__(256) void transpose_feat(const float* __restrict__ feat,
                                                      float* __restrict__ featT) {
  int g = blockIdx.x * 256 + threadIdx.x;     // < NB*NN*NC
  int c = g & 63;
  int n = (g >> 6) & 4095;
  int b = g >> 18;
  featT[g] = feat[((size_t)(b * NC + c)) * NN + n];
}

// ---------- kernel 2: farthest point sampling (R4 version, verbatim) ----------

__global__ __launch_bounds__(256) void fps_kernel(const float* __restrict__ loc,
                                                  float* __restrict__ out_setloc) {
  __shared__ float4 red[2][4];
  const int b = blockIdx.x;
  const int tid = threadIdx.x;
  const int lane = tid & 63, wid = tid >> 6;
  const float* Lx = loc + (size_t)b * 3 * NN;
  const float* Ly = Lx + NN;
  const float* Lz = Ly + NN;
  const int p0 = tid * 16;
  float px[16], py[16], pz[16], dist[16];
#pragma unroll
  for (int j4 = 0; j4 < 4; ++j4) {
    float4 vx = *(const float4*)(Lx + p0 + 4 * j4);
    float4 vy = *(const float4*)(Ly + p0 + 4 * j4);
    float4 vz = *(const float4*)(Lz + p0 + 4 * j4);
    px[4 * j4] = vx.x; px[4 * j4 + 1] = vx.y; px[4 * j4 + 2] = vx.z; px[4 * j4 + 3] = vx.w;
    py[4 * j4] = vy.x; py[4 * j4 + 1] = vy.y; py[4 * j4 + 2] = vy.z; py[4 * j4 + 3] = vy.w;
    pz[4 * j4] = vz.x; pz[4 * j4 + 1] = vz.y; pz[4 * j4 + 2] = vz.z; pz[4 * j4 + 3] = vz.w;
  }
#pragma unroll
  for (int j = 0; j < 16; ++j) dist[j] = __int_as_float(0x7f800000);
  if (tid == 0) red[1][0] = make_float4(0.0f, px[0], py[0], pz[0]);  // bootstrap: point 0
  __syncthreads();
  float4 boot = red[1][0];
  float sx = boot.y, sy = boot.z, sz = boot.w;

  float w0x = 0, w0y = 0, w0z = 0, w1x = 0, w1y = 0, w1z = 0;
  float w2x = 0, w2y = 0, w2z = 0, w3x = 0, w3y = 0, w3z = 0;
  if (tid == 0) { w0x = sx; w0y = sy; w0z = sz; }  // slot 0 = point 0

  for (int s = 0; s < NM - 1; ++s) {  // compute winners for slots 1..1023
    float bd = -1.0f, bx = 0.0f, by = 0.0f, bz = 0.0f;
#pragma unroll
    for (int j = 0; j < 16; ++j) {
      // match numpy: plain mul, left-assoc adds, no contraction
      float dx = __fsub_rn(px[j], sx);
      float dy = __fsub_rn(py[j], sy);
      float dz = __fsub_rn(pz[j], sz);
      float d2 = __fadd_rn(__fadd_rn(__fmul_rn(dx, dx), __fmul_rn(dy, dy)), __fmul_rn(dz, dz));
      float nd = fminf(dist[j], d2);
      dist[j] = nd;
      bool g = nd > bd;  // strict > keeps lowest j (= lowest index)
      bd = g ? nd : bd;
      bx = g ? px[j] : bx;
      by = g ? py[j] : by;
      bz = g ? pz[j] : bz;
    }
    float wmax = wave_fmax(bd);
    u64 m = __ballot(bd == wmax);
    if (lane == __ffsll((long long)m) - 1) red[s & 1][wid] = make_float4(bd, bx, by, bz);
    __syncthreads();
    float4 c0 = red[s & 1][0], c1 = red[s & 1][1], c2 = red[s & 1][2], c3 = red[s & 1][3];
    float bdd = c0.x; sx = c0.y; sy = c0.z; sz = c0.w;
    bool g1 = c1.x > bdd; bdd = g1 ? c1.x : bdd; sx = g1 ? c1.y : sx; sy = g1 ? c1.z : sy; sz = g1 ? c1.w : sz;
    bool g2 = c2.x > bdd; bdd = g2 ? c2.x : bdd; sx = g2 ? c2.y : sx; sy = g2 ? c2.z : sy; sz = g2 ? c2.w : sz;
    bool g3 = c3.x > bdd; bdd = g3 ? c3.x : bdd; sx = g3 ? c3.y : sx; sy = g3 ? c3.z : sy; sz = g3 ? c3.w : sz;
    if (tid == ((s + 1) & 255)) {
      w3x = w2x; w3y = w2y; w3z = w2z;
      w2x = w1x; w2y = w1y; w2z = w1z;
      w1x = w0x; w1y = w0y; w1z = w0z;
      w0x = sx;  w0y = sy;  w0z = sz;
    }
  }
  float* Ox = out_setloc + (b * 3 + 0) * NM;
  float* Oy = out_setloc + (b * 3 + 1) * NM;
  float* Oz = out_setloc + (b * 3 + 2) * NM;
  Ox[tid] = w3x;       Oy[tid] = w3y;       Oz[tid] = w3z;
  Ox[tid + 256] = w2x; Oy[tid + 256] = w2y; Oz[tid + 256] = w2z;
  Ox[tid + 512] = w1x; Oy[tid + 512] = w1y; Oz[tid + 512] = w1z;
  Ox[tid + 768] = w0x; Oy[tid + 768] = w0y; Oz[tid + 768] = w0z;
}

// ---------- kernel 3: kNN (one wave per query, DPP-min extraction) ----------

__global__ __launch_bounds__(256) void knn_kernel(const float* __restrict__ loc,
                                                  const float* __restrict__ setloc,
                                                  int* __restrict__ ws_knn) {
  const int wq = blockIdx.x * 4 + (threadIdx.x >> 6);  // query id, < NB*NM
  const int lane = threadIdx.x & 63;
  const int b = wq >> 10, mq = wq & 1023;
  const float* Sb = setloc + (size_t)b * 3 * NM;
  float xs = Sb[mq], ys = Sb[NM + mq], zs = Sb[2 * NM + mq];
  float sqs = __fadd_rn(__fadd_rn(__fmul_rn(xs, xs), __fmul_rn(ys, ys)), __fmul_rn(zs, zs));
  const float* Lx = loc + (size_t)b * 3 * NN;
  const float* Ly = Lx + NN;
  const float* Lz = Ly + NN;
  const float INF = __int_as_float(0x7f800000);

  float k1 = INF, k2 = INF;
  unsigned i1 = 0xFFFFFFFFu, i2 = 0xFFFFFFFFu;
#pragma unroll 8
  for (int j = 0; j < 64; ++j) {
    int p = j * 64 + lane;
    float x = Lx[p], y = Ly[p], z = Lz[p];
    float sql = __fadd_rn(__fadd_rn(__fmul_rn(x, x), __fmul_rn(y, y)), __fmul_rn(z, z));
    float cr  = __fadd_rn(__fadd_rn(__fmul_rn(xs, x), __fmul_rn(ys, y)), __fmul_rn(zs, z));
    float d2  = __fsub_rn(__fadd_rn(sqs, sql), __fmul_rn(2.0f, cr));
    if (d2 < k1)      { k2 = k1; i2 = i1; k1 = d2; i1 = (unsigned)p; }
    else if (d2 < k2) { k2 = d2; i2 = (unsigned)p; }
  }

  u64 used = 0;
  unsigned keep = 0;
  for (int s = 0; s < NK; ++s) {
    float wmin = wave_fmin(k1);
    u64 mask = __ballot(k1 == wmin);
    int ownerLane;
    if (__popcll(mask) > 1) {
      unsigned cand = (k1 == wmin) ? i1 : 0xFFFFFFFFu;
      unsigned minp = wave_umin(cand);
      u64 m2 = __ballot(k1 == wmin && i1 == minp);
      ownerLane = __ffsll((long long)m2) - 1;
    } else {
      ownerLane = __ffsll((long long)mask) - 1;
    }
    unsigned widx = (unsigned)__builtin_amdgcn_readlane((int)i1, ownerLane);
    if (lane == s) keep = widx;
    if (lane == ownerLane) {
      used |= 1ull << (i1 >> 6);
      k1 = k2; i1 = i2;
      k2 = INF; i2 = 0xFFFFFFFFu;
      if (__float_as_uint(k1) == 0x7f800000u) {
#pragma unroll 8
        for (int j = 0; j < 64; ++j) {
          if (!((used >> j) & 1ull)) {
            int p = j * 64 + lane;
            float x = Lx[p], y = Ly[p], z = Lz[p];
            float sql = __fadd_rn(__fadd_rn(__fmul_rn(x, x), __fmul_rn(y, y)), __fmul_rn(z, z));
            float cr  = __fadd_rn(__fadd_rn(__fmul_rn(xs, x), __fmul_rn(ys, y)), __fmul_rn(zs, z));
            float d2  = __fsub_rn(__fadd_rn(sqs, sql), __fmul_rn(2.0f, cr));
            if (d2 < k1)      { k2 = k1; i2 = i1; k1 = d2; i1 = (unsigned)p; }
            else if (d2 < k2) { k2 = d2; i2 = (unsigned)p; }
          }
        }
      }
    }
  }
  if (lane < NK) ws_knn[(size_t)wq * NK + lane] = (int)keep;
}

// ---------- kernel 4: MFMA gather + 3-layer MLP + maxpool ----------
// Block = 4 queries = 128 columns. LDS: X^T bf16 [128][KP1] (Y2 reuses it),
// Y1 [128][KP2], W tile staged per layer. Wave w owns query w (cols w*32..+31)
// end-to-end: X/Y1/Y2 are wave-private; barriers only guard W-region reuse.
// MFMA 16x16x32 bf16: A row = lane%16, k = (lane/16)*8+j (contig 8);
// B col = lane%16, same k; D col = lane&15, row = (lane>>4)*4+reg (HW-verified).

__global__ __launch_bounds__(256, 2) void mlp_mfma(
    const float* __restrict__ featT, const float* __restrict__ loc,
    const float* __restrict__ setloc, const int* __restrict__ ws_knn,
    const short* __restrict__ w1b, const short* __restrict__ w2b,
    const short* __restrict__ w3b,
    const float* __restrict__ b1, const float* __restrict__ b2,
    const float* __restrict__ b3, float* __restrict__ out) {
  __shared__ __align__(16) char lds[63488];
  short* Xl = (short*)lds;              // [128][KP1] bf16; later Y2 [128][KP2]
  short* Y1 = (short*)(lds + 26624);    // [128][KP2]
  short* Wl = (short*)(lds + 45056);    // staged weight tile (<= 18432 B)
  const int tid = threadIdx.x;
  const int lane = tid & 63;
  const int wid = tid >> 6;
  const int r = lane & 15, g = lane >> 4;

  // ---- stage X: gather 128 columns (2 threads/col), cvt bf16, zero-pad k ----
  {
    const int col = tid >> 1, half = tid & 1;
    const int qs = blockIdx.x * 4 + (col >> 5);
    const int bs = qs >> 10, mqs = qs & 1023;
    const int nk = ws_knn[(size_t)qs * NK + (col & 31)];
    const float* fsrc = featT + ((size_t)(bs * NN + nk)) * 64 + half * 32;
    short* xc = Xl + col * KP1;
#pragma unroll
    for (int i = 0; i < 4; ++i) {
      float4 va = *(const float4*)(fsrc + 8 * i);
      float4 vb = *(const float4*)(fsrc + 8 * i + 4);
      int4 w;
      w.x = pk(va.x, va.y); w.y = pk(va.z, va.w);
      w.z = pk(vb.x, vb.y); w.w = pk(vb.z, vb.w);
      *(int4*)(xc + half * 32 + 8 * i) = w;
    }
    if (half) {
      const float* Lb = loc + (size_t)bs * 3 * NN;
      const float* Sb = setloc + (size_t)bs * 3 * NM;
      float rx = Lb[nk] - Sb[mqs];
      float ry = Lb[NN + nk] - Sb[NM + mqs];
      float rz = Lb[2 * NN + nk] - Sb[2 * NM + mqs];
      int2 w; w.x = pk(rx, ry); w.y = pk(rz, 0.0f);
      *(int2*)(xc + 64) = w;                       // k = 64..67
    } else {
      *(int2*)(xc + 68) = make_int2(0, 0);         // k = 68..71
#pragma unroll
      for (int i = 0; i < 4; ++i)                  // k = 72..103
        *(int4*)(xc + 72 + 8 * i) = make_int4(0, 0, 0, 0);
    }
  }
  // stage W1 tile (64*KP1 bf16 = 13312 B = 832 int4)
  for (int t = tid; t < 832; t += 256) ((int4*)Wl)[t] = ((const int4*)w1b)[t];
  __syncthreads();

  const int n0 = wid * 32;
  const int q = blockIdx.x * 4 + wid;
  const int b = q >> 10, mq = q & 1023;

  // ---- layer 1: D[64][32] = W1[64][67+] x X[67+][32], K-steps 3 ----
  f32x4 acc1[4][2];
#pragma unroll
  for (int mt = 0; mt < 4; ++mt) {
    f32x4 bv = *(const f32x4*)(b1 + mt * 16 + g * 4);
    acc1[mt][0] = bv; acc1[mt][1] = bv;
  }
#pragma unroll
  for (int kt = 0; kt < 3; ++kt) {
    const int ko = kt * 32 + g * 8;
    bf16x8 B0 = *(const bf16x8*)(Xl + (n0 + r) * KP1 + ko);
    bf16x8 B1 = *(const bf16x8*)(Xl + (n0 + 16 + r) * KP1 + ko);
#pragma unroll
    for (int mt = 0; mt < 4; ++mt) {
      bf16x8 A = *(const bf16x8*)(Wl + (mt * 16 + r) * KP1 + ko);
      acc1[mt][0] = __builtin_amdgcn_mfma_f32_16x16x32_bf16(A, B0, acc1[mt][0], 0, 0, 0);
      acc1[mt][1] = __builtin_amdgcn_mfma_f32_16x16x32_bf16(A, B1, acc1[mt][1], 0, 0, 0);
    }
  }
  // relu + cvt + write Y1 [col][row] (wave-private)
#pragma unroll
  for (int mt = 0; mt < 4; ++mt)
#pragma unroll
    for (int nt = 0; nt < 2; ++nt) {
      f32x4 v = acc1[mt][nt];
      v[0] = fmaxf(v[0], 0.f); v[1] = fmaxf(v[1], 0.f);
      v[2] = fmaxf(v[2], 0.f); v[3] = fmaxf(v[3], 0.f);
      int2 w; w.x = pk(v[0], v[1]); w.y = pk(v[2], v[3]);
      *(int2*)(Y1 + (n0 + nt * 16 + r) * KP2 + mt * 16 + g * 4) = w;
    }
  __syncthreads();  // all waves done reading W1 tile

  // ---- layer 2: W2[64][64] x Y1 ----
  for (int t = tid; t < 576; t += 256) ((int4*)Wl)[t] = ((const int4*)w2b)[t];
  __syncthreads();
  f32x4 acc2[4][2];
#pragma unroll
  for (int mt = 0; mt < 4; ++mt) {
    f32x4 bv = *(const f32x4*)(b2 + mt * 16 + g * 4);
    acc2[mt][0] = bv; acc2[mt][1] = bv;
  }
#pragma unroll
  for (int kt = 0; kt < 2; ++kt) {
    const int ko = kt * 32 + g * 8;
    bf16x8 B0 = *(const bf16x8*)(Y1 + (n0 + r) * KP2 + ko);
    bf16x8 B1 = *(const bf16x8*)(Y1 + (n0 + 16 + r) * KP2 + ko);
#pragma unroll
    for (int mt = 0; mt < 4; ++mt) {
      bf16x8 A = *(const bf16x8*)(Wl + (mt * 16 + r) * KP2 + ko);
      acc2[mt][0] = __builtin_amdgcn_mfma_f32_16x16x32_bf16(A, B0, acc2[mt][0], 0, 0, 0);
      acc2[mt][1] = __builtin_amdgcn_mfma_f32_16x16x32_bf16(A, B1, acc2[mt][1], 0, 0, 0);
    }
  }
  // write Y2 into X region [col][KP2] (wave-private; own L1 X-reads are done)
#pragma unroll
  for (int mt = 0; mt < 4; ++mt)
#pragma unroll
    for (int nt = 0; nt < 2; ++nt) {
      f32x4 v = acc2[mt][nt];
      v[0] = fmaxf(v[0], 0.f); v[1] = fmaxf(v[1], 0.f);
      v[2] = fmaxf(v[2], 0.f); v[3] = fmaxf(v[3], 0.f);
      int2 w; w.x = pk(v[0], v[1]); w.y = pk(v[2], v[3]);
      *(int2*)(Xl + (n0 + nt * 16 + r) * KP2 + mt * 16 + g * 4) = w;
    }
  __syncthreads();  // all waves done reading W2 tile

  // ---- layer 3: W3[128][64] x Y2, fused relu + maxpool + store ----
  for (int t = tid; t < 1152; t += 256) ((int4*)Wl)[t] = ((const int4*)w3b)[t];
  __syncthreads();
  f32x4 acc3[8][2];
#pragma unroll
  for (int mt = 0; mt < 8; ++mt) {
    f32x4 bv = *(const f32x4*)(b3 + mt * 16 + g * 4);
    acc3[mt][0] = bv; acc3[mt][1] = bv;
  }
#pragma unroll
  for (int kt = 0; kt < 2; ++kt) {
    const int ko = kt * 32 + g * 8;
    bf16x8 B0 = *(const bf16x8*)(Xl + (n0 + r) * KP2 + ko);
    bf16x8 B1 = *(const bf16x8*)(Xl + (n0 + 16 + r) * KP2 + ko);
#pragma unroll
    for (int mt = 0; mt < 8; ++mt) {
      bf16x8 A = *(const bf16x8*)(Wl + (mt * 16 + r) * KP2 + ko);
      acc3[mt][0] = __builtin_amdgcn_mfma_f32_16x16x32_bf16(A, B0, acc3[mt][0], 0, 0, 0);
      acc3[mt][1] = __builtin_amdgcn_mfma_f32_16x16x32_bf16(A, B1, acc3[mt][1], 0, 0, 0);
    }
  }
  // epilogue: relu, max over the two col-tiles, then over 16 lanes (cols)
#pragma unroll
  for (int mt = 0; mt < 8; ++mt) {
    f32x4 u = acc3[mt][0], v = acc3[mt][1];
    float m0 = fmaxf(fmaxf(u[0], v[0]), 0.0f);
    float m1 = fmaxf(fmaxf(u[1], v[1]), 0.0f);
    float m2 = fmaxf(fmaxf(u[2], v[2]), 0.0f);
    float m3 = fmaxf(fmaxf(u[3], v[3]), 0.0f);
    RED16(m0); RED16(m1); RED16(m2); RED16(m3);
    if (r == 0) {
      float* op = out + ((size_t)b * 128 + mt * 16 + g * 4) * NM + mq;
      op[0] = m0; op[NM] = m1; op[2 * NM] = m2; op[3 * NM] = m3;
    }
  }
}

// ---------- launch ----------

extern "C" void kernel_launch(void* const* d_in, const int* in_sizes, int n_in,
                              void* d_out, int out_size, void* d_ws, size_t ws_size,
                              hipStream_t stream) {
  (void)in_sizes; (void)n_in; (void)out_size; (void)ws_size;
  const float* feat = (const float*)d_in[0];
  const float* loc  = (const float*)d_in[1];
  const float* W1   = (const float*)d_in[2];
  const float* b1   = (const float*)d_in[3];
  const float* W2   = (const float*)d_in[4];
  const float* b2   = (const float*)d_in[5];
  const float* W3   = (const float*)d_in[6];
  const float* b3   = (const float*)d_in[7];
  float* out = (float*)d_out;

  char* ws = (char*)d_ws;
  int*   ws_knn   = (int*)ws;                           // 2 MB
  float* ws_featT = (float*)(ws + 2097152);             // 16.75 MB
  short* ws_w1b   = (short*)(ws + 18874368);            // 64*104 bf16
  short* ws_w2b   = (short*)(ws + 18874368 + 13312);    // 64*72 bf16
  short* ws_w3b   = (short*)(ws + 18874368 + 22528);    // 128*72 bf16

  float* out_setfeat = out;                          // (16,128,1024)
  float* out_setloc  = out + (size_t)NB * 128 * NM;  // (16,3,1024)

  w_prep<<<dim3(80), dim3(256), 0, stream>>>(W1, W2, W3, ws_w1b, ws_w2b, ws_w3b);
  transpose_feat<<<dim3((NB * NN * NC) / 256), dim3(256), 0, stream>>>(feat, ws_featT);
  fps_kernel<<<dim3(NB), dim3(256), 0, stream>>>(loc, out_setloc);
  knn_kernel<<<dim3((NB * NM) / 4), dim3(256), 0, stream>>>(loc, out_setloc, ws_knn);
  mlp_mfma<<<dim3((NB * NM) / 4), dim3(256), 0, stream>>>(
      ws_featT, loc, out_setloc, ws_knn, ws_w1b, ws_w2b, ws_w3b, b1, b2, b3, out_setfeat);
}

// Round 10
// 1203.338 us; speedup vs baseline: 1.3490x; 1.0678x over previous
//
#include <hip/hip_runtime.h>
#include <cstdint>
#include <cstddef>

typedef unsigned long long u64;
typedef __attribute__((ext_vector_type(8))) short bf16x8;
typedef __attribute__((ext_vector_type(4))) float f32x4;

#define NB 16
#define NC 64
#define NN 4096
#define NM 1024
#define NK 32
#define KP1 104
#define KP2 72

// ---------- DPP wave-reduction helpers ----------

template <int C>
__device__ __forceinline__ float dppf(float x, float ident) {
  return __int_as_float(__builtin_amdgcn_update_dpp(
      __float_as_int(ident), __float_as_int(x), C, 0xf, 0xf, false));
}

template <int C>
__device__ __forceinline__ unsigned dppu(unsigned x, unsigned ident) {
  return (unsigned)__builtin_amdgcn_update_dpp(
      (int)ident, (int)x, C, 0xf, 0xf, false);
}

__device__ __forceinline__ float wave_fmax(float x) {
  const float I = __int_as_float(0xff800000);  // -inf
  x = fmaxf(x, dppf<0x111>(x, I));
  x = fmaxf(x, dppf<0x112>(x, I));
  x = fmaxf(x, dppf<0x114>(x, I));
  x = fmaxf(x, dppf<0x118>(x, I));
  x = fmaxf(x, dppf<0x142>(x, I));  // row_bcast:15
  x = fmaxf(x, dppf<0x143>(x, I));  // row_bcast:31
  return __int_as_float(__builtin_amdgcn_readlane(__float_as_int(x), 63));
}

__device__ __forceinline__ float wave_fmin(float x) {
  const float I = __int_as_float(0x7f800000);  // +inf
  x = fminf(x, dppf<0x111>(x, I));
  x = fminf(x, dppf<0x112>(x, I));
  x = fminf(x, dppf<0x114>(x, I));
  x = fminf(x, dppf<0x118>(x, I));
  x = fminf(x, dppf<0x142>(x, I));
  x = fminf(x, dppf<0x143>(x, I));
  return __int_as_float(__builtin_amdgcn_readlane(__float_as_int(x), 63));
}

__device__ __forceinline__ unsigned wave_umin(unsigned x) {
  const unsigned I = 0xFFFFFFFFu;
  unsigned t;
  t = dppu<0x111>(x, I); x = x < t ? x : t;
  t = dppu<0x112>(x, I); x = x < t ? x : t;
  t = dppu<0x114>(x, I); x = x < t ? x : t;
  t = dppu<0x118>(x, I); x = x < t ? x : t;
  t = dppu<0x142>(x, I); x = x < t ? x : t;
  t = dppu<0x143>(x, I); x = x < t ? x : t;
  return (unsigned)__builtin_amdgcn_readlane((int)x, 63);
}

// max over 16-lane group via DPP row_ror 8/4/2/1
#define RED16(m) { m = fmaxf(m, dppf<0x128>(m, 0.f)); m = fmaxf(m, dppf<0x124>(m, 0.f)); \
                   m = fmaxf(m, dppf<0x122>(m, 0.f)); m = fmaxf(m, dppf<0x121>(m, 0.f)); }

// f32 -> bf16 (RNE), pack pair
__device__ __forceinline__ unsigned short f2bf(float f) {
  unsigned u = __float_as_uint(f);
  return (unsigned short)((u + 0x7FFFu + ((u >> 16) & 1u)) >> 16);
}
__device__ __forceinline__ int pk(float a, float b) {
  return (int)f2bf(a) | ((int)f2bf(b) << 16);
}

// ---------- kernel A: FUSED fps (2 batches/block) + transpose + w_prep ----------
// blocks 0..7: fps, block handles batches 2b,2b+1 (waves 0-3 / 4-7);
// blocks 8..2055: feat transpose; blocks 2056..2065: weight bf16 prep.
// fps is latency-tail-bound; 2 waves/SIMD lets one batch's compute issue fill
// the other's DPP/ballot/barrier tail. Inner step logic is the proven R4 code.

__global__ __launch_bounds__(512) void fps_fused(
    const float* __restrict__ loc, float* __restrict__ out_setloc,
    const float* __restrict__ feat, float* __restrict__ featT,
    const float* __restrict__ W1, const float* __restrict__ W2,
    const float* __restrict__ W3, short* __restrict__ w1b,
    short* __restrict__ w2b, short* __restrict__ w3b) {
  const int tid = threadIdx.x;
  if (blockIdx.x >= 8) {
    if (blockIdx.x < 2056) {
      // transpose role: 2048 elements per block
      const int base = (blockIdx.x - 8) * 2048;
#pragma unroll
      for (int it = 0; it < 4; ++it) {
        int g = base + it * 512 + tid;
        int c = g & 63;
        int n = (g >> 6) & 4095;
        int b = g >> 18;
        featT[g] = feat[((size_t)(b * NC + c)) * NN + n];
      }
    } else {
      // w_prep role: 20480 elements over 10 blocks
      const int base = (blockIdx.x - 2056) * 2048;
#pragma unroll
      for (int it = 0; it < 4; ++it) {
        int gg = base + it * 512 + tid;
        if (gg < 64 * KP1) {
          int r = gg / KP1, k = gg - r * KP1;
          w1b[gg] = (k < 67) ? (short)f2bf(W1[r * 67 + k]) : (short)0;
        } else if (gg < 64 * KP1 + 64 * KP2) {
          int g2 = gg - 64 * KP1;
          int r = g2 / KP2, k = g2 - r * KP2;
          w2b[g2] = (k < 64) ? (short)f2bf(W2[r * 64 + k]) : (short)0;
        } else if (gg < 64 * KP1 + 64 * KP2 + 128 * KP2) {
          int g3 = gg - 64 * KP1 - 64 * KP2;
          int r = g3 / KP2, k = g3 - r * KP2;
          w3b[g3] = (k < 64) ? (short)f2bf(W3[r * 64 + k]) : (short)0;
        }
      }
    }
    return;
  }

  // ---- fps role ----
  __shared__ float4 red[2][2][4];  // [batch-half][dbuf][wave-in-batch]
  const int half = tid >> 8;       // 0/1: which batch
  const int ltid = tid & 255;      // batch-local tid
  const int b = blockIdx.x * 2 + half;
  const int lane = tid & 63, wid4 = (tid >> 6) & 3;
  const float* Lx = loc + (size_t)b * 3 * NN;
  const float* Ly = Lx + NN;
  const float* Lz = Ly + NN;
  const int p0 = ltid * 16;
  float px[16], py[16], pz[16], dist[16];
#pragma unroll
  for (int j4 = 0; j4 < 4; ++j4) {
    float4 vx = *(const float4*)(Lx + p0 + 4 * j4);
    float4 vy = *(const float4*)(Ly + p0 + 4 * j4);
    float4 vz = *(const float4*)(Lz + p0 + 4 * j4);
    px[4 * j4] = vx.x; px[4 * j4 + 1] = vx.y; px[4 * j4 + 2] = vx.z; px[4 * j4 + 3] = vx.w;
    py[4 * j4] = vy.x; py[4 * j4 + 1] = vy.y; py[4 * j4 + 2] = vy.z; py[4 * j4 + 3] = vy.w;
    pz[4 * j4] = vz.x; pz[4 * j4 + 1] = vz.y; pz[4 * j4 + 2] = vz.z; pz[4 * j4 + 3] = vz.w;
  }
#pragma unroll
  for (int j = 0; j < 16; ++j) dist[j] = __int_as_float(0x7f800000);
  if (ltid == 0) red[half][1][0] = make_float4(0.0f, px[0], py[0], pz[0]);  // bootstrap
  __syncthreads();
  float4 boot = red[half][1][0];
  float sx = boot.y, sy = boot.z, sz = boot.w;

  float w0x = 0, w0y = 0, w0z = 0, w1x = 0, w1y = 0, w1z = 0;
  float w2x = 0, w2y = 0, w2z = 0, w3x = 0, w3y = 0, w3z = 0;
  if (ltid == 0) { w0x = sx; w0y = sy; w0z = sz; }  // slot 0 = point 0

  for (int s = 0; s < NM - 1; ++s) {  // winners for slots 1..1023
    float bd = -1.0f, bx = 0.0f, by = 0.0f, bz = 0.0f;
#pragma unroll
    for (int j = 0; j < 16; ++j) {
      // match numpy: plain mul, left-assoc adds, no contraction
      float dx = __fsub_rn(px[j], sx);
      float dy = __fsub_rn(py[j], sy);
      float dz = __fsub_rn(pz[j], sz);
      float d2 = __fadd_rn(__fadd_rn(__fmul_rn(dx, dx), __fmul_rn(dy, dy)), __fmul_rn(dz, dz));
      float nd = fminf(dist[j], d2);
      dist[j] = nd;
      bool g = nd > bd;  // strict > keeps lowest j (= lowest index)
      bd = g ? nd : bd;
      bx = g ? px[j] : bx;
      by = g ? py[j] : by;
      bz = g ? pz[j] : bz;
    }
    float wmax = wave_fmax(bd);
    u64 m = __ballot(bd == wmax);
    if (lane == __ffsll((long long)m) - 1) red[half][s & 1][wid4] = make_float4(bd, bx, by, bz);
    __syncthreads();
    float4 c0 = red[half][s & 1][0], c1 = red[half][s & 1][1];
    float4 c2 = red[half][s & 1][2], c3 = red[half][s & 1][3];
    float bdd = c0.x; sx = c0.y; sy = c0.z; sz = c0.w;
    bool g1 = c1.x > bdd; bdd = g1 ? c1.x : bdd; sx = g1 ? c1.y : sx; sy = g1 ? c1.z : sy; sz = g1 ? c1.w : sz;
    bool g2 = c2.x > bdd; bdd = g2 ? c2.x : bdd; sx = g2 ? c2.y : sx; sy = g2 ? c2.z : sy; sz = g2 ? c2.w : sz;
    bool g3 = c3.x > bdd; bdd = g3 ? c3.x : bdd; sx = g3 ? c3.y : sx; sy = g3 ? c3.z : sy; sz = g3 ? c3.w : sz;
    if (ltid == ((s + 1) & 255)) {
      w3x = w2x; w3y = w2y; w3z = w2z;
      w2x = w1x; w2y = w1y; w2z = w1z;
      w1x = w0x; w1y = w0y; w1z = w0z;
      w0x = sx;  w0y = sy;  w0z = sz;
    }
  }
  float* Ox = out_setloc + (b * 3 + 0) * NM;
  float* Oy = out_setloc + (b * 3 + 1) * NM;
  float* Oz = out_setloc + (b * 3 + 2) * NM;
  Ox[ltid] = w3x;       Oy[ltid] = w3y;       Oz[ltid] = w3z;
  Ox[ltid + 256] = w2x; Oy[ltid + 256] = w2y; Oz[ltid + 256] = w2z;
  Ox[ltid + 512] = w1x; Oy[ltid + 512] = w1y; Oz[ltid + 512] = w1z;
  Ox[ltid + 768] = w0x; Oy[ltid + 768] = w0y; Oz[ltid + 768] = w0z;
}

// ---------- kernel B: kNN (one wave per query, per-lane TOP-4 cache) ----------
// Top-4 (was top-2) drops expected refills 6/wave -> ~0.1/wave; each refill is
// a ~2000cyc exec-masked full rescan, which was ~80% of knn's runtime.

__global__ __launch_bounds__(256) void knn_kernel(const float* __restrict__ loc,
                                                  const float* __restrict__ setloc,
                                                  int* __restrict__ ws_knn) {
  const int wq = blockIdx.x * 4 + (threadIdx.x >> 6);  // query id, < NB*NM
  const int lane = threadIdx.x & 63;
  const int b = wq >> 10, mq = wq & 1023;
  const float* Sb = setloc + (size_t)b * 3 * NM;
  float xs = Sb[mq], ys = Sb[NM + mq], zs = Sb[2 * NM + mq];
  float sqs = __fadd_rn(__fadd_rn(__fmul_rn(xs, xs), __fmul_rn(ys, ys)), __fmul_rn(zs, zs));
  const float* Lx = loc + (size_t)b * 3 * NN;
  const float* Ly = Lx + NN;
  const float* Lz = Ly + NN;
  const float INF = __int_as_float(0x7f800000);

  // per-lane four smallest (value, index), sorted ascending; strict < keeps
  // first-occurrence (lowest p) ahead on equal values.
  float k1 = INF, k2 = INF, k3 = INF, k4 = INF;
  unsigned i1 = 0xFFFFFFFFu, i2 = 0xFFFFFFFFu, i3 = 0xFFFFFFFFu, i4 = 0xFFFFFFFFu;
#pragma unroll 8
  for (int j = 0; j < 64; ++j) {
    unsigned p = (unsigned)(j * 64 + lane);
    float x = Lx[p], y = Ly[p], z = Lz[p];
    float sql = __fadd_rn(__fadd_rn(__fmul_rn(x, x), __fmul_rn(y, y)), __fmul_rn(z, z));
    float cr  = __fadd_rn(__fadd_rn(__fmul_rn(xs, x), __fmul_rn(ys, y)), __fmul_rn(zs, z));
    float d2  = __fsub_rn(__fadd_rn(sqs, sql), __fmul_rn(2.0f, cr));
    bool c1 = d2 < k1, c2 = d2 < k2, c3 = d2 < k3, c4 = d2 < k4;
    k4 = c3 ? k3 : (c4 ? d2 : k4);  i4 = c3 ? i3 : (c4 ? p : i4);
    k3 = c2 ? k2 : (c3 ? d2 : k3);  i3 = c2 ? i2 : (c3 ? p : i3);
    k2 = c1 ? k1 : (c2 ? d2 : k2);  i2 = c1 ? i1 : (c2 ? p : i2);
    k1 = c1 ? d2 : k1;              i1 = c1 ? p  : i1;
  }

  u64 used = 0;        // per-lane mask of extracted j-slots
  unsigned keep = 0;   // lane s holds round-s winner
  for (int s = 0; s < NK; ++s) {
    float wmin = wave_fmin(k1);
    u64 mask = __ballot(k1 == wmin);
    int ownerLane;
    if (__popcll(mask) > 1) {
      // exact tie-break: smallest global index among tied lanes
      unsigned cand = (k1 == wmin) ? i1 : 0xFFFFFFFFu;
      unsigned minp = wave_umin(cand);
      u64 m2 = __ballot(k1 == wmin && i1 == minp);
      ownerLane = __ffsll((long long)m2) - 1;
    } else {
      ownerLane = __ffsll((long long)mask) - 1;
    }
    unsigned widx = (unsigned)__builtin_amdgcn_readlane((int)i1, ownerLane);
    if (lane == s) keep = widx;
    if (lane == ownerLane) {
      used |= 1ull << (i1 >> 6);
      k1 = k2; i1 = i2; k2 = k3; i2 = i3; k3 = k4; i3 = i4;
      k4 = INF; i4 = 0xFFFFFFFFu;
      if (__float_as_uint(k1) == 0x7f800000u) {
        // ultra-rare refill (lane won 4+ rounds): rebuild top-4 from scratch
#pragma unroll 8
        for (int j = 0; j < 64; ++j) {
          if (!((used >> j) & 1ull)) {
            unsigned p = (unsigned)(j * 64 + lane);
            float x = Lx[p], y = Ly[p], z = Lz[p];
            float sql = __fadd_rn(__fadd_rn(__fmul_rn(x, x), __fmul_rn(y, y)), __fmul_rn(z, z));
            float cr  = __fadd_rn(__fadd_rn(__fmul_rn(xs, x), __fmul_rn(ys, y)), __fmul_rn(zs, z));
            float d2  = __fsub_rn(__fadd_rn(sqs, sql), __fmul_rn(2.0f, cr));
            bool c1 = d2 < k1, c2 = d2 < k2, c3 = d2 < k3, c4 = d2 < k4;
            k4 = c3 ? k3 : (c4 ? d2 : k4);  i4 = c3 ? i3 : (c4 ? p : i4);
            k3 = c2 ? k2 : (c3 ? d2 : k3);  i3 = c2 ? i2 : (c3 ? p : i3);
            k2 = c1 ? k1 : (c2 ? d2 : k2);  i2 = c1 ? i1 : (c2 ? p : i2);
            k1 = c1 ? d2 : k1;              i1 = c1 ? p  : i1;
          }
        }
      }
    }
  }
  if (lane < NK) ws_knn[(size_t)wq * NK + lane] = (int)keep;
}

// ---------- kernel C: MFMA gather + 3-layer MLP + maxpool (R9, verbatim) ----------

__global__ __launch_bounds__(256, 2) void mlp_mfma(
    const float* __restrict__ featT, const float* __restrict__ loc,
    const float* __restrict__ setloc, const int* __restrict__ ws_knn,
    const short* __restrict__ w1b, const short* __restrict__ w2b,
    const short* __restrict__ w3b,
    const float* __restrict__ b1, const float* __restrict__ b2,
    const float* __restrict__ b3, float* __restrict__ out) {
  __shared__ __align__(16) char lds[63488];
  short* Xl = (short*)lds;              // [128][KP1] bf16; later Y2 [128][KP2]
  short* Y1 = (short*)(lds + 26624);    // [128][KP2]
  short* Wl = (short*)(lds + 45056);    // staged weight tile (<= 18432 B)
  const int tid = threadIdx.x;
  const int lane = tid & 63;
  const int wid = tid >> 6;
  const int r = lane & 15, g = lane >> 4;

  // ---- stage X: gather 128 columns (2 threads/col), cvt bf16, zero-pad k ----
  {
    const int col = tid >> 1, half = tid & 1;
    const int qs = blockIdx.x * 4 + (col >> 5);
    const int bs = qs >> 10, mqs = qs & 1023;
    const int nk = ws_knn[(size_t)qs * NK + (col & 31)];
    const float* fsrc = featT + ((size_t)(bs * NN + nk)) * 64 + half * 32;
    short* xc = Xl + col * KP1;
#pragma unroll
    for (int i = 0; i < 4; ++i) {
      float4 va = *(const float4*)(fsrc + 8 * i);
      float4 vb = *(const float4*)(fsrc + 8 * i + 4);
      int4 w;
      w.x = pk(va.x, va.y); w.y = pk(va.z, va.w);
      w.z = pk(vb.x, vb.y); w.w = pk(vb.z, vb.w);
      *(int4*)(xc + half * 32 + 8 * i) = w;
    }
    if (half) {
      const float* Lb = loc + (size_t)bs * 3 * NN;
      const float* Sb = setloc + (size_t)bs * 3 * NM;
      float rx = Lb[nk] - Sb[mqs];
      float ry = Lb[NN + nk] - Sb[NM + mqs];
      float rz = Lb[2 * NN + nk] - Sb[2 * NM + mqs];
      int2 w; w.x = pk(rx, ry); w.y = pk(rz, 0.0f);
      *(int2*)(xc + 64) = w;                       // k = 64..67
    } else {
      *(int2*)(xc + 68) = make_int2(0, 0);         // k = 68..71
#pragma unroll
      for (int i = 0; i < 4; ++i)                  // k = 72..103
        *(int4*)(xc + 72 + 8 * i) = make_int4(0, 0, 0, 0);
    }
  }
  // stage W1 tile (64*KP1 bf16 = 13312 B = 832 int4)
  for (int t = tid; t < 832; t += 256) ((int4*)Wl)[t] = ((const int4*)w1b)[t];
  __syncthreads();

  const int n0 = wid * 32;
  const int q = blockIdx.x * 4 + wid;
  const int b = q >> 10, mq = q & 1023;

  // ---- layer 1: D[64][32] = W1[64][67+] x X[67+][32], K-steps 3 ----
  f32x4 acc1[4][2];
#pragma unroll
  for (int mt = 0; mt < 4; ++mt) {
    f32x4 bv = *(const f32x4*)(b1 + mt * 16 + g * 4);
    acc1[mt][0] = bv; acc1[mt][1] = bv;
  }
#pragma unroll
  for (int kt = 0; kt < 3; ++kt) {
    const int ko = kt * 32 + g * 8;
    bf16x8 B0 = *(const bf16x8*)(Xl + (n0 + r) * KP1 + ko);
    bf16x8 B1 = *(const bf16x8*)(Xl + (n0 + 16 + r) * KP1 + ko);
#pragma unroll
    for (int mt = 0; mt < 4; ++mt) {
      bf16x8 A = *(const bf16x8*)(Wl + (mt * 16 + r) * KP1 + ko);
      acc1[mt][0] = __builtin_amdgcn_mfma_f32_16x16x32_bf16(A, B0, acc1[mt][0], 0, 0, 0);
      acc1[mt][1] = __builtin_amdgcn_mfma_f32_16x16x32_bf16(A, B1, acc1[mt][1], 0, 0, 0);
    }
  }
#pragma unroll
  for (int mt = 0; mt < 4; ++mt)
#pragma unroll
    for (int nt = 0; nt < 2; ++nt) {
      f32x4 v = acc1[mt][nt];
      v[0] = fmaxf(v[0], 0.f); v[1] = fmaxf(v[1], 0.f);
      v[2] = fmaxf(v[2], 0.f); v[3] = fmaxf(v[3], 0.f);
      int2 w; w.x = pk(v[0], v[1]); w.y = pk(v[2], v[3]);
      *(int2*)(Y1 + (n0 + nt * 16 + r) * KP2 + mt * 16 + g * 4) = w;
    }
  __syncthreads();  // all waves done reading W1 tile

  // ---- layer 2: W2[64][64] x Y1 ----
  for (int t = tid; t < 576; t += 256) ((int4*)Wl)[t] = ((const int4*)w2b)[t];
  __syncthreads();
  f32x4 acc2[4][2];
#pragma unroll
  for (int mt = 0; mt < 4; ++mt) {
    f32x4 bv = *(const f32x4*)(b2 + mt * 16 + g * 4);
    acc2[mt][0] = bv; acc2[mt][1] = bv;
  }
#pragma unroll
  for (int kt = 0; kt < 2; ++kt) {
    const int ko = kt * 32 + g * 8;
    bf16x8 B0 = *(const bf16x8*)(Y1 + (n0 + r) * KP2 + ko);
    bf16x8 B1 = *(const bf16x8*)(Y1 + (n0 + 16 + r) * KP2 + ko);
#pragma unroll
    for (int mt = 0; mt < 4; ++mt) {
      bf16x8 A = *(const bf16x8*)(Wl + (mt * 16 + r) * KP2 + ko);
      acc2[mt][0] = __builtin_amdgcn_mfma_f32_16x16x32_bf16(A, B0, acc2[mt][0], 0, 0, 0);
      acc2[mt][1] = __builtin_amdgcn_mfma_f32_16x16x32_bf16(A, B1, acc2[mt][1], 0, 0, 0);
    }
  }
#pragma unroll
  for (int mt = 0; mt < 4; ++mt)
#pragma unroll
    for (int nt = 0; nt < 2; ++nt) {
      f32x4 v = acc2[mt][nt];
      v[0] = fmaxf(v[0], 0.f); v[1] = fmaxf(v[1], 0.f);
      v[2] = fmaxf(v[2], 0.f); v[3] = fmaxf(v[3], 0.f);
      int2 w; w.x = pk(v[0], v[1]); w.y = pk(v[2], v[3]);
      *(int2*)(Xl + (n0 + nt * 16 + r) * KP2 + mt * 16 + g * 4) = w;
    }
  __syncthreads();  // all waves done reading W2 tile

  // ---- layer 3: W3[128][64] x Y2, fused relu + maxpool + store ----
  for (int t = tid; t < 1152; t += 256) ((int4*)Wl)[t] = ((const int4*)w3b)[t];
  __syncthreads();
  f32x4 acc3[8][2];
#pragma unroll
  for (int mt = 0; mt < 8; ++mt) {
    f32x4 bv = *(const f32x4*)(b3 + mt * 16 + g * 4);
    acc3[mt][0] = bv; acc3[mt][1] = bv;
  }
#pragma unroll
  for (int kt = 0; kt < 2; ++kt) {
    const int ko = kt * 32 + g * 8;
    bf16x8 B0 = *(const bf16x8*)(Xl + (n0 + r) * KP2 + ko);
    bf16x8 B1 = *(const bf16x8*)(Xl + (n0 + 16 + r) * KP2 + ko);
#pragma unroll
    for (int mt = 0; mt < 8; ++mt) {
      bf16x8 A = *(const bf16x8*)(Wl + (mt * 16 + r) * KP2 + ko);
      acc3[mt][0] = __builtin_amdgcn_mfma_f32_16x16x32_bf16(A, B0, acc3[mt][0], 0, 0, 0);
      acc3[mt][1] = __builtin_amdgcn_mfma_f32_16x16x32_bf16(A, B1, acc3[mt][1], 0, 0, 0);
    }
  }
#pragma unroll
  for (int mt = 0; mt < 8; ++mt) {
    f32x4 u = acc3[mt][0], v = acc3[mt][1];
    float m0 = fmaxf(fmaxf(u[0], v[0]), 0.0f);
    float m1 = fmaxf(fmaxf(u[1], v[1]), 0.0f);
    float m2 = fmaxf(fmaxf(u[2], v[2]), 0.0f);
    float m3 = fmaxf(fmaxf(u[3], v[3]), 0.0f);
    RED16(m0); RED16(m1); RED16(m2); RED16(m3);
    if (r == 0) {
      float* op = out + ((size_t)b * 128 + mt * 16 + g * 4) * NM + mq;
      op[0] = m0; op[NM] = m1; op[2 * NM] = m2; op[3 * NM] = m3;
    }
  }
}

// ---------- launch ----------

extern "C" void kernel_launch(void* const* d_in, const int* in_sizes, int n_in,
                              void* d_out, int out_size, void* d_ws, size_t ws_size,
                              hipStream_t stream) {
  (void)in_sizes; (void)n_in; (void)out_size; (void)ws_size;
  const float* feat = (const float*)d_in[0];
  const float* loc  = (const float*)d_in[1];
  const float* W1   = (const float*)d_in[2];
  const float* b1   = (const float*)d_in[3];
  const float* W2   = (const float*)d_in[4];
  const float* b2   = (const float*)d_in[5];
  const float* W3   = (const float*)d_in[6];
  const float* b3   = (const float*)d_in[7];
  float* out = (float*)d_out;

  char* ws = (char*)d_ws;
  int*   ws_knn   = (int*)ws;                           // 2 MB
  float* ws_featT = (float*)(ws + 2097152);             // 16.75 MB
  short* ws_w1b   = (short*)(ws + 18874368);            // 64*104 bf16
  short* ws_w2b   = (short*)(ws + 18874368 + 13312);    // 64*72 bf16
  short* ws_w3b   = (short*)(ws + 18874368 + 22528);    // 128*72 bf16

  float* out_setfeat = out;                          // (16,128,1024)
  float* out_setloc  = out + (size_t)NB * 128 * NM;  // (16,3,1024)

  fps_fused<<<dim3(2066), dim3(512), 0, stream>>>(
      loc, out_setloc, feat, ws_featT, W1, W2, W3, ws_w1b, ws_w2b, ws_w3b);
  knn_kernel<<<dim3((NB * NM) / 4), dim3(256), 0, stream>>>(loc, out_setloc, ws_knn);
  mlp_mfma<<<dim3((NB * NM) / 4), dim3(256), 0, stream>>>(
      ws_featT, loc, out_setloc, ws_knn, ws_w1b, ws_w2b, ws_w3b, b1, b2, b3, out_setfeat);
}

// Round 11
// 977.804 us; speedup vs baseline: 1.6602x; 1.2307x over previous
//
#include <hip/hip_runtime.h>
#include <cstdint>
#include <cstddef>

typedef unsigned long long u64;
typedef __attribute__((ext_vector_type(8))) short bf16x8;
typedef __attribute__((ext_vector_type(4))) float f32x4;

#define NB 16
#define NC 64
#define NN 4096
#define NM 1024
#define NK 32
#define KP1 104
#define KP2 72

// ---------- DPP wave-reduction helpers ----------

template <int C>
__device__ __forceinline__ float dppf(float x, float ident) {
  return __int_as_float(__builtin_amdgcn_update_dpp(
      __float_as_int(ident), __float_as_int(x), C, 0xf, 0xf, false));
}

template <int C>
__device__ __forceinline__ unsigned dppu(unsigned x, unsigned ident) {
  return (unsigned)__builtin_amdgcn_update_dpp(
      (int)ident, (int)x, C, 0xf, 0xf, false);
}

__device__ __forceinline__ float wave_fmax(float x) {
  const float I = __int_as_float(0xff800000);  // -inf
  x = fmaxf(x, dppf<0x111>(x, I));
  x = fmaxf(x, dppf<0x112>(x, I));
  x = fmaxf(x, dppf<0x114>(x, I));
  x = fmaxf(x, dppf<0x118>(x, I));
  x = fmaxf(x, dppf<0x142>(x, I));  // row_bcast:15
  x = fmaxf(x, dppf<0x143>(x, I));  // row_bcast:31
  return __int_as_float(__builtin_amdgcn_readlane(__float_as_int(x), 63));
}

__device__ __forceinline__ float wave_fmin(float x) {
  const float I = __int_as_float(0x7f800000);  // +inf
  x = fminf(x, dppf<0x111>(x, I));
  x = fminf(x, dppf<0x112>(x, I));
  x = fminf(x, dppf<0x114>(x, I));
  x = fminf(x, dppf<0x118>(x, I));
  x = fminf(x, dppf<0x142>(x, I));
  x = fminf(x, dppf<0x143>(x, I));
  return __int_as_float(__builtin_amdgcn_readlane(__float_as_int(x), 63));
}

__device__ __forceinline__ unsigned wave_umin(unsigned x) {
  const unsigned I = 0xFFFFFFFFu;
  unsigned t;
  t = dppu<0x111>(x, I); x = x < t ? x : t;
  t = dppu<0x112>(x, I); x = x < t ? x : t;
  t = dppu<0x114>(x, I); x = x < t ? x : t;
  t = dppu<0x118>(x, I); x = x < t ? x : t;
  t = dppu<0x142>(x, I); x = x < t ? x : t;
  t = dppu<0x143>(x, I); x = x < t ? x : t;
  return (unsigned)__builtin_amdgcn_readlane((int)x, 63);
}

// max over 16-lane group via DPP row_ror 8/4/2/1
#define RED16(m) { m = fmaxf(m, dppf<0x128>(m, 0.f)); m = fmaxf(m, dppf<0x124>(m, 0.f)); \
                   m = fmaxf(m, dppf<0x122>(m, 0.f)); m = fmaxf(m, dppf<0x121>(m, 0.f)); }

// f32 -> bf16 (RNE), pack pair
__device__ __forceinline__ unsigned short f2bf(float f) {
  unsigned u = __float_as_uint(f);
  return (unsigned short)((u + 0x7FFFu + ((u >> 16) & 1u)) >> 16);
}
__device__ __forceinline__ int pk(float a, float b) {
  return (int)f2bf(a) | ((int)f2bf(b) << 16);
}

// ---------- kernel A: FUSED fps (1 batch / 256-thr block) + transpose + w_prep ----------
// blocks 0..15: fps; 16..2063: feat transpose; 2064..2073: weight bf16 prep.
// fps scan is a PURE FMAX chain (no coord/index tracking: -4 VALU/pt and the
// serial 16x(cmp+4cndmask) chain -> 16x fmax). Owner lane rebuilds the winning
// j from dist[]==wmax (exec-masked, one wave/step), passes (val,idx) float2;
// winner coords come from an LDS copy of the points (3 broadcast ds_read).

__global__ __launch_bounds__(256) void fps_fused(
    const float* __restrict__ loc, float* __restrict__ out_setloc,
    const float* __restrict__ feat, float* __restrict__ featT,
    const float* __restrict__ W1, const float* __restrict__ W2,
    const float* __restrict__ W3, short* __restrict__ w1b,
    short* __restrict__ w2b, short* __restrict__ w3b) {
  __shared__ __align__(16) float lx[NN];
  __shared__ __align__(16) float ly[NN];
  __shared__ __align__(16) float lz[NN];
  __shared__ float2 red[2][4];
  const int tid = threadIdx.x;

  if (blockIdx.x >= 16) {
    if (blockIdx.x < 2064) {
      // transpose role: 2048 elements per block
      const int base = (blockIdx.x - 16) * 2048;
#pragma unroll
      for (int it = 0; it < 8; ++it) {
        int g = base + it * 256 + tid;
        int c = g & 63;
        int n = (g >> 6) & 4095;
        int b = g >> 18;
        featT[g] = feat[((size_t)(b * NC + c)) * NN + n];
      }
    } else {
      // w_prep role: 20480 elements over 10 blocks
      const int base = (blockIdx.x - 2064) * 2048;
#pragma unroll
      for (int it = 0; it < 8; ++it) {
        int gg = base + it * 256 + tid;
        if (gg < 64 * KP1) {
          int r = gg / KP1, k = gg - r * KP1;
          w1b[gg] = (k < 67) ? (short)f2bf(W1[r * 67 + k]) : (short)0;
        } else if (gg < 64 * KP1 + 64 * KP2) {
          int g2 = gg - 64 * KP1;
          int r = g2 / KP2, k = g2 - r * KP2;
          w2b[g2] = (k < 64) ? (short)f2bf(W2[r * 64 + k]) : (short)0;
        } else if (gg < 64 * KP1 + 64 * KP2 + 128 * KP2) {
          int g3 = gg - 64 * KP1 - 64 * KP2;
          int r = g3 / KP2, k = g3 - r * KP2;
          w3b[g3] = (k < 64) ? (short)f2bf(W3[r * 64 + k]) : (short)0;
        }
      }
    }
    return;
  }

  // ---- fps role: one batch per block ----
  const int b = blockIdx.x;
  const int lane = tid & 63, wid = tid >> 6;
  const float* Lx = loc + (size_t)b * 3 * NN;
  const float* Ly = Lx + NN;
  const float* Lz = Ly + NN;
  const int p0 = tid * 16;
  float px[16], py[16], pz[16], dist[16];
#pragma unroll
  for (int j4 = 0; j4 < 4; ++j4) {
    float4 vx = *(const float4*)(Lx + p0 + 4 * j4);
    float4 vy = *(const float4*)(Ly + p0 + 4 * j4);
    float4 vz = *(const float4*)(Lz + p0 + 4 * j4);
    *(float4*)(lx + p0 + 4 * j4) = vx;
    *(float4*)(ly + p0 + 4 * j4) = vy;
    *(float4*)(lz + p0 + 4 * j4) = vz;
    px[4 * j4] = vx.x; px[4 * j4 + 1] = vx.y; px[4 * j4 + 2] = vx.z; px[4 * j4 + 3] = vx.w;
    py[4 * j4] = vy.x; py[4 * j4 + 1] = vy.y; py[4 * j4 + 2] = vy.z; py[4 * j4 + 3] = vy.w;
    pz[4 * j4] = vz.x; pz[4 * j4 + 1] = vz.y; pz[4 * j4 + 2] = vz.z; pz[4 * j4 + 3] = vz.w;
  }
#pragma unroll
  for (int j = 0; j < 16; ++j) dist[j] = __int_as_float(0x7f800000);
  __syncthreads();
  float sx = lx[0], sy = ly[0], sz = lz[0];  // bootstrap: point 0 (broadcast)

  // register shift-queue of captured winners (slot s captured by tid == s%256)
  float w0x = 0, w0y = 0, w0z = 0, w1x = 0, w1y = 0, w1z = 0;
  float w2x = 0, w2y = 0, w2z = 0, w3x = 0, w3y = 0, w3z = 0;
  if (tid == 0) { w0x = sx; w0y = sy; w0z = sz; }  // slot 0 = point 0

  for (int s = 0; s < NM - 1; ++s) {  // winners for slots 1..1023
    // distance update + pure value-max chain (exact numpy arithmetic)
    float bd = __int_as_float(0xff800000);
#pragma unroll
    for (int j = 0; j < 16; ++j) {
      float dx = __fsub_rn(px[j], sx);
      float dy = __fsub_rn(py[j], sy);
      float dz = __fsub_rn(pz[j], sz);
      float d2 = __fadd_rn(__fadd_rn(__fmul_rn(dx, dx), __fmul_rn(dy, dy)), __fmul_rn(dz, dz));
      float nd = fminf(dist[j], d2);
      dist[j] = nd;
      bd = fmaxf(bd, nd);
    }
    float wmax = wave_fmax(bd);
    u64 m = __ballot(bd == wmax);
    if (lane == __ffsll((long long)m) - 1) {
      // owner lane: find FIRST j with dist[j] == wmax (lowest index wins)
      unsigned msk = 0;
#pragma unroll
      for (int j = 0; j < 16; ++j) msk |= (dist[j] == wmax) ? (1u << j) : 0u;
      int jj = __ffs(msk) - 1;
      red[s & 1][wid] = make_float2(wmax, __int_as_float(p0 + jj));
    }
    __syncthreads();
    // stage 2: 4 candidates, strict > ascending wid == global first-max
    float2 c0 = red[s & 1][0], c1 = red[s & 1][1], c2 = red[s & 1][2], c3 = red[s & 1][3];
    float bv = c0.x; int ci = __float_as_int(c0.y);
    bool g1 = c1.x > bv; bv = g1 ? c1.x : bv; ci = g1 ? __float_as_int(c1.y) : ci;
    bool g2 = c2.x > bv; bv = g2 ? c2.x : bv; ci = g2 ? __float_as_int(c2.y) : ci;
    bool g3 = c3.x > bv; bv = g3 ? c3.x : bv; ci = g3 ? __float_as_int(c3.y) : ci;
    // winner coords via LDS broadcast
    sx = lx[ci]; sy = ly[ci]; sz = lz[ci];
    // capture slot s+1 into the shift queue (static indices only)
    if (tid == ((s + 1) & 255)) {
      w3x = w2x; w3y = w2y; w3z = w2z;
      w2x = w1x; w2y = w1y; w2z = w1z;
      w1x = w0x; w1y = w0y; w1z = w0z;
      w0x = sx;  w0y = sy;  w0z = sz;
    }
  }
  // thread t holds slots t(w3), t+256(w2), t+512(w1), t+768(w0); coalesced write
  float* Ox = out_setloc + (b * 3 + 0) * NM;
  float* Oy = out_setloc + (b * 3 + 1) * NM;
  float* Oz = out_setloc + (b * 3 + 2) * NM;
  Ox[tid] = w3x;       Oy[tid] = w3y;       Oz[tid] = w3z;
  Ox[tid + 256] = w2x; Oy[tid + 256] = w2y; Oz[tid + 256] = w2z;
  Ox[tid + 512] = w1x; Oy[tid + 512] = w1y; Oz[tid + 512] = w1z;
  Ox[tid + 768] = w0x; Oy[tid + 768] = w0y; Oz[tid + 768] = w0z;
}

// ---------- kernel B: kNN (one wave per query, per-lane TOP-4 cache) ----------

__global__ __launch_bounds__(256) void knn_kernel(const float* __restrict__ loc,
                                                  const float* __restrict__ setloc,
                                                  int* __restrict__ ws_knn) {
  const int wq = blockIdx.x * 4 + (threadIdx.x >> 6);  // query id, < NB*NM
  const int lane = threadIdx.x & 63;
  const int b = wq >> 10, mq = wq & 1023;
  const float* Sb = setloc + (size_t)b * 3 * NM;
  float xs = Sb[mq], ys = Sb[NM + mq], zs = Sb[2 * NM + mq];
  float sqs = __fadd_rn(__fadd_rn(__fmul_rn(xs, xs), __fmul_rn(ys, ys)), __fmul_rn(zs, zs));
  const float* Lx = loc + (size_t)b * 3 * NN;
  const float* Ly = Lx + NN;
  const float* Lz = Ly + NN;
  const float INF = __int_as_float(0x7f800000);

  float k1 = INF, k2 = INF, k3 = INF, k4 = INF;
  unsigned i1 = 0xFFFFFFFFu, i2 = 0xFFFFFFFFu, i3 = 0xFFFFFFFFu, i4 = 0xFFFFFFFFu;
#pragma unroll 8
  for (int j = 0; j < 64; ++j) {
    unsigned p = (unsigned)(j * 64 + lane);
    float x = Lx[p], y = Ly[p], z = Lz[p];
    float sql = __fadd_rn(__fadd_rn(__fmul_rn(x, x), __fmul_rn(y, y)), __fmul_rn(z, z));
    float cr  = __fadd_rn(__fadd_rn(__fmul_rn(xs, x), __fmul_rn(ys, y)), __fmul_rn(zs, z));
    float d2  = __fsub_rn(__fadd_rn(sqs, sql), __fmul_rn(2.0f, cr));
    bool c1 = d2 < k1, c2 = d2 < k2, c3 = d2 < k3, c4 = d2 < k4;
    k4 = c3 ? k3 : (c4 ? d2 : k4);  i4 = c3 ? i3 : (c4 ? p : i4);
    k3 = c2 ? k2 : (c3 ? d2 : k3);  i3 = c2 ? i2 : (c3 ? p : i3);
    k2 = c1 ? k1 : (c2 ? d2 : k2);  i2 = c1 ? i1 : (c2 ? p : i2);
    k1 = c1 ? d2 : k1;              i1 = c1 ? p  : i1;
  }

  u64 used = 0;
  unsigned keep = 0;
  for (int s = 0; s < NK; ++s) {
    float wmin = wave_fmin(k1);
    u64 mask = __ballot(k1 == wmin);
    int ownerLane;
    if (__popcll(mask) > 1) {
      unsigned cand = (k1 == wmin) ? i1 : 0xFFFFFFFFu;
      unsigned minp = wave_umin(cand);
      u64 m2 = __ballot(k1 == wmin && i1 == minp);
      ownerLane = __ffsll((long long)m2) - 1;
    } else {
      ownerLane = __ffsll((long long)mask) - 1;
    }
    unsigned widx = (unsigned)__builtin_amdgcn_readlane((int)i1, ownerLane);
    if (lane == s) keep = widx;
    if (lane == ownerLane) {
      used |= 1ull << (i1 >> 6);
      k1 = k2; i1 = i2; k2 = k3; i2 = i3; k3 = k4; i3 = i4;
      k4 = INF; i4 = 0xFFFFFFFFu;
      if (__float_as_uint(k1) == 0x7f800000u) {
#pragma unroll 8
        for (int j = 0; j < 64; ++j) {
          if (!((used >> j) & 1ull)) {
            unsigned p = (unsigned)(j * 64 + lane);
            float x = Lx[p], y = Ly[p], z = Lz[p];
            float sql = __fadd_rn(__fadd_rn(__fmul_rn(x, x), __fmul_rn(y, y)), __fmul_rn(z, z));
            float cr  = __fadd_rn(__fadd_rn(__fmul_rn(xs, x), __fmul_rn(ys, y)), __fmul_rn(zs, z));
            float d2  = __fsub_rn(__fadd_rn(sqs, sql), __fmul_rn(2.0f, cr));
            bool c1 = d2 < k1, c2 = d2 < k2, c3 = d2 < k3, c4 = d2 < k4;
            k4 = c3 ? k3 : (c4 ? d2 : k4);  i4 = c3 ? i3 : (c4 ? p : i4);
            k3 = c2 ? k2 : (c3 ? d2 : k3);  i3 = c2 ? i2 : (c3 ? p : i3);
            k2 = c1 ? k1 : (c2 ? d2 : k2);  i2 = c1 ? i1 : (c2 ? p : i2);
            k1 = c1 ? d2 : k1;              i1 = c1 ? p  : i1;
          }
        }
      }
    }
  }
  if (lane < NK) ws_knn[(size_t)wq * NK + lane] = (int)keep;
}

// ---------- kernel C: MFMA gather + 3-layer MLP + maxpool (R9, verbatim) ----------

__global__ __launch_bounds__(256, 2) void mlp_mfma(
    const float* __restrict__ featT, const float* __restrict__ loc,
    const float* __restrict__ setloc, const int* __restrict__ ws_knn,
    const short* __restrict__ w1b, const short* __restrict__ w2b,
    const short* __restrict__ w3b,
    const float* __restrict__ b1, const float* __restrict__ b2,
    const float* __restrict__ b3, float* __restrict__ out) {
  __shared__ __align__(16) char lds[63488];
  short* Xl = (short*)lds;              // [128][KP1] bf16; later Y2 [128][KP2]
  short* Y1 = (short*)(lds + 26624);    // [128][KP2]
  short* Wl = (short*)(lds + 45056);    // staged weight tile (<= 18432 B)
  const int tid = threadIdx.x;
  const int lane = tid & 63;
  const int wid = tid >> 6;
  const int r = lane & 15, g = lane >> 4;

  // ---- stage X: gather 128 columns (2 threads/col), cvt bf16, zero-pad k ----
  {
    const int col = tid >> 1, half = tid & 1;
    const int qs = blockIdx.x * 4 + (col >> 5);
    const int bs = qs >> 10, mqs = qs & 1023;
    const int nk = ws_knn[(size_t)qs * NK + (col & 31)];
    const float* fsrc = featT + ((size_t)(bs * NN + nk)) * 64 + half * 32;
    short* xc = Xl + col * KP1;
#pragma unroll
    for (int i = 0; i < 4; ++i) {
      float4 va = *(const float4*)(fsrc + 8 * i);
      float4 vb = *(const float4*)(fsrc + 8 * i + 4);
      int4 w;
      w.x = pk(va.x, va.y); w.y = pk(va.z, va.w);
      w.z = pk(vb.x, vb.y); w.w = pk(vb.z, vb.w);
      *(int4*)(xc + half * 32 + 8 * i) = w;
    }
    if (half) {
      const float* Lb = loc + (size_t)bs * 3 * NN;
      const float* Sb = setloc + (size_t)bs * 3 * NM;
      float rx = Lb[nk] - Sb[mqs];
      float ry = Lb[NN + nk] - Sb[NM + mqs];
      float rz = Lb[2 * NN + nk] - Sb[2 * NM + mqs];
      int2 w; w.x = pk(rx, ry); w.y = pk(rz, 0.0f);
      *(int2*)(xc + 64) = w;                       // k = 64..67
    } else {
      *(int2*)(xc + 68) = make_int2(0, 0);         // k = 68..71
#pragma unroll
      for (int i = 0; i < 4; ++i)                  // k = 72..103
        *(int4*)(xc + 72 + 8 * i) = make_int4(0, 0, 0, 0);
    }
  }
  // stage W1 tile (64*KP1 bf16 = 13312 B = 832 int4)
  for (int t = tid; t < 832; t += 256) ((int4*)Wl)[t] = ((const int4*)w1b)[t];
  __syncthreads();

  const int n0 = wid * 32;
  const int q = blockIdx.x * 4 + wid;
  const int b = q >> 10, mq = q & 1023;

  // ---- layer 1: D[64][32] = W1[64][67+] x X[67+][32], K-steps 3 ----
  f32x4 acc1[4][2];
#pragma unroll
  for (int mt = 0; mt < 4; ++mt) {
    f32x4 bv = *(const f32x4*)(b1 + mt * 16 + g * 4);
    acc1[mt][0] = bv; acc1[mt][1] = bv;
  }
#pragma unroll
  for (int kt = 0; kt < 3; ++kt) {
    const int ko = kt * 32 + g * 8;
    bf16x8 B0 = *(const bf16x8*)(Xl + (n0 + r) * KP1 + ko);
    bf16x8 B1 = *(const bf16x8*)(Xl + (n0 + 16 + r) * KP1 + ko);
#pragma unroll
    for (int mt = 0; mt < 4; ++mt) {
      bf16x8 A = *(const bf16x8*)(Wl + (mt * 16 + r) * KP1 + ko);
      acc1[mt][0] = __builtin_amdgcn_mfma_f32_16x16x32_bf16(A, B0, acc1[mt][0], 0, 0, 0);
      acc1[mt][1] = __builtin_amdgcn_mfma_f32_16x16x32_bf16(A, B1, acc1[mt][1], 0, 0, 0);
    }
  }
#pragma unroll
  for (int mt = 0; mt < 4; ++mt)
#pragma unroll
    for (int nt = 0; nt < 2; ++nt) {
      f32x4 v = acc1[mt][nt];
      v[0] = fmaxf(v[0], 0.f); v[1] = fmaxf(v[1], 0.f);
      v[2] = fmaxf(v[2], 0.f); v[3] = fmaxf(v[3], 0.f);
      int2 w; w.x = pk(v[0], v[1]); w.y = pk(v[2], v[3]);
      *(int2*)(Y1 + (n0 + nt * 16 + r) * KP2 + mt * 16 + g * 4) = w;
    }
  __syncthreads();  // all waves done reading W1 tile

  // ---- layer 2: W2[64][64] x Y1 ----
  for (int t = tid; t < 576; t += 256) ((int4*)Wl)[t] = ((const int4*)w2b)[t];
  __syncthreads();
  f32x4 acc2[4][2];
#pragma unroll
  for (int mt = 0; mt < 4; ++mt) {
    f32x4 bv = *(const f32x4*)(b2 + mt * 16 + g * 4);
    acc2[mt][0] = bv; acc2[mt][1] = bv;
  }
#pragma unroll
  for (int kt = 0; kt < 2; ++kt) {
    const int ko = kt * 32 + g * 8;
    bf16x8 B0 = *(const bf16x8*)(Y1 + (n0 + r) * KP2 + ko);
    bf16x8 B1 = *(const bf16x8*)(Y1 + (n0 + 16 + r) * KP2 + ko);
#pragma unroll
    for (int mt = 0; mt < 4; ++mt) {
      bf16x8 A = *(const bf16x8*)(Wl + (mt * 16 + r) * KP2 + ko);
      acc2[mt][0] = __builtin_amdgcn_mfma_f32_16x16x32_bf16(A, B0, acc2[mt][0], 0, 0, 0);
      acc2[mt][1] = __builtin_amdgcn_mfma_f32_16x16x32_bf16(A, B1, acc2[mt][1], 0, 0, 0);
    }
  }
#pragma unroll
  for (int mt = 0; mt < 4; ++mt)
#pragma unroll
    for (int nt = 0; nt < 2; ++nt) {
      f32x4 v = acc2[mt][nt];
      v[0] = fmaxf(v[0], 0.f); v[1] = fmaxf(v[1], 0.f);
      v[2] = fmaxf(v[2], 0.f); v[3] = fmaxf(v[3], 0.f);
      int2 w; w.x = pk(v[0], v[1]); w.y = pk(v[2], v[3]);
      *(int2*)(Xl + (n0 + nt * 16 + r) * KP2 + mt * 16 + g * 4) = w;
    }
  __syncthreads();  // all waves done reading W2 tile

  // ---- layer 3: W3[128][64] x Y2, fused relu + maxpool + store ----
  for (int t = tid; t < 1152; t += 256) ((int4*)Wl)[t] = ((const int4*)w3b)[t];
  __syncthreads();
  f32x4 acc3[8][2];
#pragma unroll
  for (int mt = 0; mt < 8; ++mt) {
    f32x4 bv = *(const f32x4*)(b3 + mt * 16 + g * 4);
    acc3[mt][0] = bv; acc3[mt][1] = bv;
  }
#pragma unroll
  for (int kt = 0; kt < 2; ++kt) {
    const int ko = kt * 32 + g * 8;
    bf16x8 B0 = *(const bf16x8*)(Xl + (n0 + r) * KP2 + ko);
    bf16x8 B1 = *(const bf16x8*)(Xl + (n0 + 16 + r) * KP2 + ko);
#pragma unroll
    for (int mt = 0; mt < 8; ++mt) {
      bf16x8 A = *(const bf16x8*)(Wl + (mt * 16 + r) * KP2 + ko);
      acc3[mt][0] = __builtin_amdgcn_mfma_f32_16x16x32_bf16(A, B0, acc3[mt][0], 0, 0, 0);
      acc3[mt][1] = __builtin_amdgcn_mfma_f32_16x16x32_bf16(A, B1, acc3[mt][1], 0, 0, 0);
    }
  }
#pragma unroll
  for (int mt = 0; mt < 8; ++mt) {
    f32x4 u = acc3[mt][0], v = acc3[mt][1];
    float m0 = fmaxf(fmaxf(u[0], v[0]), 0.0f);
    float m1 = fmaxf(fmaxf(u[1], v[1]), 0.0f);
    float m2 = fmaxf(fmaxf(u[2], v[2]), 0.0f);
    float m3 = fmaxf(fmaxf(u[3], v[3]), 0.0f);
    RED16(m0); RED16(m1); RED16(m2); RED16(m3);
    if (r == 0) {
      float* op = out + ((size_t)b * 128 + mt * 16 + g * 4) * NM + mq;
      op[0] = m0; op[NM] = m1; op[2 * NM] = m2; op[3 * NM] = m3;
    }
  }
}

// ---------- launch ----------

extern "C" void kernel_launch(void* const* d_in, const int* in_sizes, int n_in,
                              void* d_out, int out_size, void* d_ws, size_t ws_size,
                              hipStream_t stream) {
  (void)in_sizes; (void)n_in; (void)out_size; (void)ws_size;
  const float* feat = (const float*)d_in[0];
  const float* loc  = (const float*)d_in[1];
  const float* W1   = (const float*)d_in[2];
  const float* b1   = (const float*)d_in[3];
  const float* W2   = (const float*)d_in[4];
  const float* b2   = (const float*)d_in[5];
  const float* W3   = (const float*)d_in[6];
  const float* b3   = (const float*)d_in[7];
  float* out = (float*)d_out;

  char* ws = (char*)d_ws;
  int*   ws_knn   = (int*)ws;                           // 2 MB
  float* ws_featT = (float*)(ws + 2097152);             // 16.75 MB
  short* ws_w1b   = (short*)(ws + 18874368);            // 64*104 bf16
  short* ws_w2b   = (short*)(ws + 18874368 + 13312);    // 64*72 bf16
  short* ws_w3b   = (short*)(ws + 18874368 + 22528);    // 128*72 bf16

  float* out_setfeat = out;                          // (16,128,1024)
  float* out_setloc  = out + (size_t)NB * 128 * NM;  // (16,3,1024)

  fps_fused<<<dim3(2074), dim3(256), 0, stream>>>(
      loc, out_setloc, feat, ws_featT, W1, W2, W3, ws_w1b, ws_w2b, ws_w3b);
  knn_kernel<<<dim3((NB * NM) / 4), dim3(256), 0, stream>>>(loc, out_setloc, ws_knn);
  mlp_mfma<<<dim3((NB * NM) / 4), dim3(256), 0, stream>>>(
      ws_featT, loc, out_setloc, ws_knn, ws_w1b, ws_w2b, ws_w3b, b1, b2, b3, out_setfeat);
}

// Round 13
// 957.767 us; speedup vs baseline: 1.6949x; 1.0209x over previous
//
#include <hip/hip_runtime.h>
#include <cstdint>
#include <cstddef>

typedef unsigned long long u64;
typedef __attribute__((ext_vector_type(8))) short bf16x8;
typedef __attribute__((ext_vector_type(4))) float f32x4;
typedef __attribute__((ext_vector_type(2))) float f32x2;

#define NB 16
#define NC 64
#define NN 4096
#define NM 1024
#define NK 32
#define KP1 104
#define KP2 72

// ---------- DPP wave-reduction helpers ----------

template <int C>
__device__ __forceinline__ float dppf(float x, float ident) {
  return __int_as_float(__builtin_amdgcn_update_dpp(
      __float_as_int(ident), __float_as_int(x), C, 0xf, 0xf, false));
}

template <int C>
__device__ __forceinline__ unsigned dppu(unsigned x, unsigned ident) {
  return (unsigned)__builtin_amdgcn_update_dpp(
      (int)ident, (int)x, C, 0xf, 0xf, false);
}

__device__ __forceinline__ float wave_fmax(float x) {
  const float I = __int_as_float(0xff800000);  // -inf
  x = fmaxf(x, dppf<0x111>(x, I));
  x = fmaxf(x, dppf<0x112>(x, I));
  x = fmaxf(x, dppf<0x114>(x, I));
  x = fmaxf(x, dppf<0x118>(x, I));
  x = fmaxf(x, dppf<0x142>(x, I));  // row_bcast:15
  x = fmaxf(x, dppf<0x143>(x, I));  // row_bcast:31
  return __int_as_float(__builtin_amdgcn_readlane(__float_as_int(x), 63));
}

__device__ __forceinline__ float wave_fmin(float x) {
  const float I = __int_as_float(0x7f800000);  // +inf
  x = fminf(x, dppf<0x111>(x, I));
  x = fminf(x, dppf<0x112>(x, I));
  x = fminf(x, dppf<0x114>(x, I));
  x = fminf(x, dppf<0x118>(x, I));
  x = fminf(x, dppf<0x142>(x, I));
  x = fminf(x, dppf<0x143>(x, I));
  return __int_as_float(__builtin_amdgcn_readlane(__float_as_int(x), 63));
}

__device__ __forceinline__ unsigned wave_umin(unsigned x) {
  const unsigned I = 0xFFFFFFFFu;
  unsigned t;
  t = dppu<0x111>(x, I); x = x < t ? x : t;
  t = dppu<0x112>(x, I); x = x < t ? x : t;
  t = dppu<0x114>(x, I); x = x < t ? x : t;
  t = dppu<0x118>(x, I); x = x < t ? x : t;
  t = dppu<0x142>(x, I); x = x < t ? x : t;
  t = dppu<0x143>(x, I); x = x < t ? x : t;
  return (unsigned)__builtin_amdgcn_readlane((int)x, 63);
}

// max over 16-lane group via DPP row_ror 8/4/2/1
#define RED16(m) { m = fmaxf(m, dppf<0x128>(m, 0.f)); m = fmaxf(m, dppf<0x124>(m, 0.f)); \
                   m = fmaxf(m, dppf<0x122>(m, 0.f)); m = fmaxf(m, dppf<0x121>(m, 0.f)); }

// f32 -> bf16 (RNE), pack pair
__device__ __forceinline__ unsigned short f2bf(float f) {
  unsigned u = __float_as_uint(f);
  return (unsigned short)((u + 0x7FFFu + ((u >> 16) & 1u)) >> 16);
}
__device__ __forceinline__ int pk(float a, float b) {
  return (int)f2bf(a) | ((int)f2bf(b) << 16);
}

// ---------- kernel A: FUSED fps + transpose + w_prep ----------
// blocks 0..15: fps; 16..2063: feat transpose; 2064..2073: weight bf16 prep.
// fps: packed-f32 scan (v_pk_* halves issue; fp contract OFF preserves exact
// numpy rounding); owner lane finds first-j, fetches coords from LDS copy
// PRE-barrier, writes float4 (val,x,y,z); stage-2 = one LDS read + 3 selects.

__global__ __launch_bounds__(256) void fps_fused(
    const float* __restrict__ loc, float* __restrict__ out_setloc,
    const float* __restrict__ feat, float* __restrict__ featT,
    const float* __restrict__ W1, const float* __restrict__ W2,
    const float* __restrict__ W3, short* __restrict__ w1b,
    short* __restrict__ w2b, short* __restrict__ w3b) {
  __shared__ __align__(16) float lx[NN];
  __shared__ __align__(16) float ly[NN];
  __shared__ __align__(16) float lz[NN];
  __shared__ float4 red[2][4];
  const int tid = threadIdx.x;

  if (blockIdx.x >= 16) {
    if (blockIdx.x < 2064) {
      // transpose role: 2048 elements per block
      const int base = (blockIdx.x - 16) * 2048;
#pragma unroll
      for (int it = 0; it < 8; ++it) {
        int g = base + it * 256 + tid;
        int c = g & 63;
        int n = (g >> 6) & 4095;
        int b = g >> 18;
        featT[g] = feat[((size_t)(b * NC + c)) * NN + n];
      }
    } else {
      // w_prep role: 20480 elements over 10 blocks
      const int base = (blockIdx.x - 2064) * 2048;
#pragma unroll
      for (int it = 0; it < 8; ++it) {
        int gg = base + it * 256 + tid;
        if (gg < 64 * KP1) {
          int r = gg / KP1, k = gg - r * KP1;
          w1b[gg] = (k < 67) ? (short)f2bf(W1[r * 67 + k]) : (short)0;
        } else if (gg < 64 * KP1 + 64 * KP2) {
          int g2 = gg - 64 * KP1;
          int r = g2 / KP2, k = g2 - r * KP2;
          w2b[g2] = (k < 64) ? (short)f2bf(W2[r * 64 + k]) : (short)0;
        } else if (gg < 64 * KP1 + 64 * KP2 + 128 * KP2) {
          int g3 = gg - 64 * KP1 - 64 * KP2;
          int r = g3 / KP2, k = g3 - r * KP2;
          w3b[g3] = (k < 64) ? (short)f2bf(W3[r * 64 + k]) : (short)0;
        }
      }
    }
    return;
  }

  // ---- fps role: one batch per block ----
  {
    // CRITICAL: no fma contraction -- the discrete argmax must reproduce
    // numpy's exact per-op rounding (mul, add, add; left-assoc).
#pragma clang fp contract(off)
    const int b = blockIdx.x;
    const int lane = tid & 63, wid = tid >> 6;
    const float* Lx = loc + (size_t)b * 3 * NN;
    const float* Ly = Lx + NN;
    const float* Lz = Ly + NN;
    const int p0 = tid * 16;
    f32x2 px2[8], py2[8], pz2[8], dist2[8];
#pragma unroll
    for (int j4 = 0; j4 < 4; ++j4) {
      float4 vx = *(const float4*)(Lx + p0 + 4 * j4);
      float4 vy = *(const float4*)(Ly + p0 + 4 * j4);
      float4 vz = *(const float4*)(Lz + p0 + 4 * j4);
      *(float4*)(lx + p0 + 4 * j4) = vx;
      *(float4*)(ly + p0 + 4 * j4) = vy;
      *(float4*)(lz + p0 + 4 * j4) = vz;
      px2[2 * j4]     = (f32x2){vx.x, vx.y};
      px2[2 * j4 + 1] = (f32x2){vx.z, vx.w};
      py2[2 * j4]     = (f32x2){vy.x, vy.y};
      py2[2 * j4 + 1] = (f32x2){vy.z, vy.w};
      pz2[2 * j4]     = (f32x2){vz.x, vz.y};
      pz2[2 * j4 + 1] = (f32x2){vz.z, vz.w};
    }
    const float PINF = __int_as_float(0x7f800000);
#pragma unroll
    for (int j = 0; j < 8; ++j) dist2[j] = (f32x2){PINF, PINF};
    __syncthreads();
    float sx = lx[0], sy = ly[0], sz = lz[0];  // bootstrap: point 0

    // register shift-queue of captured winners (slot s captured by tid==s%256)
    float w0x = 0, w0y = 0, w0z = 0, w1x = 0, w1y = 0, w1z = 0;
    float w2x = 0, w2y = 0, w2z = 0, w3x = 0, w3y = 0, w3z = 0;
    if (tid == 0) { w0x = sx; w0y = sy; w0z = sz; }  // slot 0 = point 0

    for (int s = 0; s < NM - 1; ++s) {  // winners for slots 1..1023
      const f32x2 sxv = (f32x2){sx, sx};
      const f32x2 syv = (f32x2){sy, sy};
      const f32x2 szv = (f32x2){sz, sz};
      f32x2 bd2 = (f32x2){__int_as_float(0xff800000), __int_as_float(0xff800000)};
#pragma unroll
      for (int j = 0; j < 8; ++j) {
        f32x2 dx = px2[j] - sxv;
        f32x2 dy = py2[j] - syv;
        f32x2 dz = pz2[j] - szv;
        f32x2 d2 = (dx * dx + dy * dy) + dz * dz;  // contract OFF: exact numpy
        f32x2 nd = __builtin_elementwise_min(dist2[j], d2);
        dist2[j] = nd;
        bd2 = __builtin_elementwise_max(bd2, nd);
      }
      float bd = fmaxf(bd2.x, bd2.y);
      float wmax = wave_fmax(bd);
      u64 m = __ballot(bd == wmax);
      if (lane == __ffsll((long long)m) - 1) {
        // owner: first j with dist == wmax (lowest index), coords pre-barrier
        unsigned msk = 0;
#pragma unroll
        for (int j = 0; j < 8; ++j) {
          msk |= (dist2[j].x == wmax) ? (1u << (2 * j)) : 0u;
          msk |= (dist2[j].y == wmax) ? (1u << (2 * j + 1)) : 0u;
        }
        int ci = p0 + (__ffs(msk) - 1);
        red[s & 1][wid] = make_float4(wmax, lx[ci], ly[ci], lz[ci]);
      }
      __syncthreads();
      // stage 2: 4 candidates, strict > ascending wid == global first-max
      float4 c0 = red[s & 1][0], c1 = red[s & 1][1], c2 = red[s & 1][2], c3 = red[s & 1][3];
      float bdd = c0.x; sx = c0.y; sy = c0.z; sz = c0.w;
      bool g1 = c1.x > bdd; bdd = g1 ? c1.x : bdd; sx = g1 ? c1.y : sx; sy = g1 ? c1.z : sy; sz = g1 ? c1.w : sz;
      bool g2 = c2.x > bdd; bdd = g2 ? c2.x : bdd; sx = g2 ? c2.y : sx; sy = g2 ? c2.z : sy; sz = g2 ? c2.w : sz;
      bool g3 = c3.x > bdd; bdd = g3 ? c3.x : bdd; sx = g3 ? c3.y : sx; sy = g3 ? c3.z : sy; sz = g3 ? c3.w : sz;
      // capture slot s+1 into the shift queue (static indices only)
      if (tid == ((s + 1) & 255)) {
        w3x = w2x; w3y = w2y; w3z = w2z;
        w2x = w1x; w2y = w1y; w2z = w1z;
        w1x = w0x; w1y = w0y; w1z = w0z;
        w0x = sx;  w0y = sy;  w0z = sz;
      }
    }
    // thread t holds slots t(w3), t+256(w2), t+512(w1), t+768(w0)
    float* Ox = out_setloc + (b * 3 + 0) * NM;
    float* Oy = out_setloc + (b * 3 + 1) * NM;
    float* Oz = out_setloc + (b * 3 + 2) * NM;
    Ox[tid] = w3x;       Oy[tid] = w3y;       Oz[tid] = w3z;
    Ox[tid + 256] = w2x; Oy[tid + 256] = w2y; Oz[tid + 256] = w2z;
    Ox[tid + 512] = w1x; Oy[tid + 512] = w1y; Oz[tid + 512] = w1z;
    Ox[tid + 768] = w0x; Oy[tid + 768] = w0y; Oz[tid + 768] = w0z;
  }
}

// ---------- kernel B: kNN (one wave per query, per-lane TOP-4 cache) ----------

__global__ __launch_bounds__(256) void knn_kernel(const float* __restrict__ loc,
                                                  const float* __restrict__ setloc,
                                                  int* __restrict__ ws_knn) {
  const int wq = blockIdx.x * 4 + (threadIdx.x >> 6);  // query id, < NB*NM
  const int lane = threadIdx.x & 63;
  const int b = wq >> 10, mq = wq & 1023;
  const float* Sb = setloc + (size_t)b * 3 * NM;
  float xs = Sb[mq], ys = Sb[NM + mq], zs = Sb[2 * NM + mq];
  float sqs = __fadd_rn(__fadd_rn(__fmul_rn(xs, xs), __fmul_rn(ys, ys)), __fmul_rn(zs, zs));
  const float* Lx = loc + (size_t)b * 3 * NN;
  const float* Ly = Lx + NN;
  const float* Lz = Ly + NN;
  const float INF = __int_as_float(0x7f800000);

  float k1 = INF, k2 = INF, k3 = INF, k4 = INF;
  unsigned i1 = 0xFFFFFFFFu, i2 = 0xFFFFFFFFu, i3 = 0xFFFFFFFFu, i4 = 0xFFFFFFFFu;
#pragma unroll 8
  for (int j = 0; j < 64; ++j) {
    unsigned p = (unsigned)(j * 64 + lane);
    float x = Lx[p], y = Ly[p], z = Lz[p];
    float sql = __fadd_rn(__fadd_rn(__fmul_rn(x, x), __fmul_rn(y, y)), __fmul_rn(z, z));
    float cr  = __fadd_rn(__fadd_rn(__fmul_rn(xs, x), __fmul_rn(ys, y)), __fmul_rn(zs, z));
    float d2  = __fsub_rn(__fadd_rn(sqs, sql), __fmul_rn(2.0f, cr));
    bool c1 = d2 < k1, c2 = d2 < k2, c3 = d2 < k3, c4 = d2 < k4;
    k4 = c3 ? k3 : (c4 ? d2 : k4);  i4 = c3 ? i3 : (c4 ? p : i4);
    k3 = c2 ? k2 : (c3 ? d2 : k3);  i3 = c2 ? i2 : (c3 ? p : i3);
    k2 = c1 ? k1 : (c2 ? d2 : k2);  i2 = c1 ? i1 : (c2 ? p : i2);
    k1 = c1 ? d2 : k1;              i1 = c1 ? p  : i1;
  }

  u64 used = 0;
  unsigned keep = 0;
  for (int s = 0; s < NK; ++s) {
    float wmin = wave_fmin(k1);
    u64 mask = __ballot(k1 == wmin);
    int ownerLane;
    if (__popcll(mask) > 1) {
      unsigned cand = (k1 == wmin) ? i1 : 0xFFFFFFFFu;
      unsigned minp = wave_umin(cand);
      u64 m2 = __ballot(k1 == wmin && i1 == minp);
      ownerLane = __ffsll((long long)m2) - 1;
    } else {
      ownerLane = __ffsll((long long)mask) - 1;
    }
    unsigned widx = (unsigned)__builtin_amdgcn_readlane((int)i1, ownerLane);
    if (lane == s) keep = widx;
    if (lane == ownerLane) {
      used |= 1ull << (i1 >> 6);
      k1 = k2; i1 = i2; k2 = k3; i2 = i3; k3 = k4; i3 = i4;
      k4 = INF; i4 = 0xFFFFFFFFu;
      if (__float_as_uint(k1) == 0x7f800000u) {
#pragma unroll 8
        for (int j = 0; j < 64; ++j) {
          if (!((used >> j) & 1ull)) {
            unsigned p = (unsigned)(j * 64 + lane);
            float x = Lx[p], y = Ly[p], z = Lz[p];
            float sql = __fadd_rn(__fadd_rn(__fmul_rn(x, x), __fmul_rn(y, y)), __fmul_rn(z, z));
            float cr  = __fadd_rn(__fadd_rn(__fmul_rn(xs, x), __fmul_rn(ys, y)), __fmul_rn(zs, z));
            float d2  = __fsub_rn(__fadd_rn(sqs, sql), __fmul_rn(2.0f, cr));
            bool c1 = d2 < k1, c2 = d2 < k2, c3 = d2 < k3, c4 = d2 < k4;
            k4 = c3 ? k3 : (c4 ? d2 : k4);  i4 = c3 ? i3 : (c4 ? p : i4);
            k3 = c2 ? k2 : (c3 ? d2 : k3);  i3 = c2 ? i2 : (c3 ? p : i3);
            k2 = c1 ? k1 : (c2 ? d2 : k2);  i2 = c1 ? i1 : (c2 ? p : i2);
            k1 = c1 ? d2 : k1;              i1 = c1 ? p  : i1;
          }
        }
      }
    }
  }
  if (lane < NK) ws_knn[(size_t)wq * NK + lane] = (int)keep;
}

// ---------- kernel C: MFMA gather + 3-layer MLP + maxpool (R9, verbatim) ----------

__global__ __launch_bounds__(256, 2) void mlp_mfma(
    const float* __restrict__ featT, const float* __restrict__ loc,
    const float* __restrict__ setloc, const int* __restrict__ ws_knn,
    const short* __restrict__ w1b, const short* __restrict__ w2b,
    const short* __restrict__ w3b,
    const float* __restrict__ b1, const float* __restrict__ b2,
    const float* __restrict__ b3, float* __restrict__ out) {
  __shared__ __align__(16) char lds[63488];
  short* Xl = (short*)lds;              // [128][KP1] bf16; later Y2 [128][KP2]
  short* Y1 = (short*)(lds + 26624);    // [128][KP2]
  short* Wl = (short*)(lds + 45056);    // staged weight tile (<= 18432 B)
  const int tid = threadIdx.x;
  const int lane = tid & 63;
  const int wid = tid >> 6;
  const int r = lane & 15, g = lane >> 4;

  // ---- stage X: gather 128 columns (2 threads/col), cvt bf16, zero-pad k ----
  {
    const int col = tid >> 1, half = tid & 1;
    const int qs = blockIdx.x * 4 + (col >> 5);
    const int bs = qs >> 10, mqs = qs & 1023;
    const int nk = ws_knn[(size_t)qs * NK + (col & 31)];
    const float* fsrc = featT + ((size_t)(bs * NN + nk)) * 64 + half * 32;
    short* xc = Xl + col * KP1;
#pragma unroll
    for (int i = 0; i < 4; ++i) {
      float4 va = *(const float4*)(fsrc + 8 * i);
      float4 vb = *(const float4*)(fsrc + 8 * i + 4);
      int4 w;
      w.x = pk(va.x, va.y); w.y = pk(va.z, va.w);
      w.z = pk(vb.x, vb.y); w.w = pk(vb.z, vb.w);
      *(int4*)(xc + half * 32 + 8 * i) = w;
    }
    if (half) {
      const float* Lb = loc + (size_t)bs * 3 * NN;
      const float* Sb = setloc + (size_t)bs * 3 * NM;
      float rx = Lb[nk] - Sb[mqs];
      float ry = Lb[NN + nk] - Sb[NM + mqs];
      float rz = Lb[2 * NN + nk] - Sb[2 * NM + mqs];
      int2 w; w.x = pk(rx, ry); w.y = pk(rz, 0.0f);
      *(int2*)(xc + 64) = w;                       // k = 64..67
    } else {
      *(int2*)(xc + 68) = make_int2(0, 0);         // k = 68..71
#pragma unroll
      for (int i = 0; i < 4; ++i)                  // k = 72..103
        *(int4*)(xc + 72 + 8 * i) = make_int4(0, 0, 0, 0);
    }
  }
  // stage W1 tile (64*KP1 bf16 = 13312 B = 832 int4)
  for (int t = tid; t < 832; t += 256) ((int4*)Wl)[t] = ((const int4*)w1b)[t];
  __syncthreads();

  const int n0 = wid * 32;
  const int q = blockIdx.x * 4 + wid;
  const int b = q >> 10, mq = q & 1023;

  // ---- layer 1: D[64][32] = W1[64][67+] x X[67+][32], K-steps 3 ----
  f32x4 acc1[4][2];
#pragma unroll
  for (int mt = 0; mt < 4; ++mt) {
    f32x4 bv = *(const f32x4*)(b1 + mt * 16 + g * 4);
    acc1[mt][0] = bv; acc1[mt][1] = bv;
  }
#pragma unroll
  for (int kt = 0; kt < 3; ++kt) {
    const int ko = kt * 32 + g * 8;
    bf16x8 B0 = *(const bf16x8*)(Xl + (n0 + r) * KP1 + ko);
    bf16x8 B1 = *(const bf16x8*)(Xl + (n0 + 16 + r) * KP1 + ko);
#pragma unroll
    for (int mt = 0; mt < 4; ++mt) {
      bf16x8 A = *(const bf16x8*)(Wl + (mt * 16 + r) * KP1 + ko);
      acc1[mt][0] = __builtin_amdgcn_mfma_f32_16x16x32_bf16(A, B0, acc1[mt][0], 0, 0, 0);
      acc1[mt][1] = __builtin_amdgcn_mfma_f32_16x16x32_bf16(A, B1, acc1[mt][1], 0, 0, 0);
    }
  }
#pragma unroll
  for (int mt = 0; mt < 4; ++mt)
#pragma unroll
    for (int nt = 0; nt < 2; ++nt) {
      f32x4 v = acc1[mt][nt];
      v[0] = fmaxf(v[0], 0.f); v[1] = fmaxf(v[1], 0.f);
      v[2] = fmaxf(v[2], 0.f); v[3] = fmaxf(v[3], 0.f);
      int2 w; w.x = pk(v[0], v[1]); w.y = pk(v[2], v[3]);
      *(int2*)(Y1 + (n0 + nt * 16 + r) * KP2 + mt * 16 + g * 4) = w;
    }
  __syncthreads();  // all waves done reading W1 tile

  // ---- layer 2: W2[64][64] x Y1 ----
  for (int t = tid; t < 576; t += 256) ((int4*)Wl)[t] = ((const int4*)w2b)[t];
  __syncthreads();
  f32x4 acc2[4][2];
#pragma unroll
  for (int mt = 0; mt < 4; ++mt) {
    f32x4 bv = *(const f32x4*)(b2 + mt * 16 + g * 4);
    acc2[mt][0] = bv; acc2[mt][1] = bv;
  }
#pragma unroll
  for (int kt = 0; kt < 2; ++kt) {
    const int ko = kt * 32 + g * 8;
    bf16x8 B0 = *(const bf16x8*)(Y1 + (n0 + r) * KP2 + ko);
    bf16x8 B1 = *(const bf16x8*)(Y1 + (n0 + 16 + r) * KP2 + ko);
#pragma unroll
    for (int mt = 0; mt < 4; ++mt) {
      bf16x8 A = *(const bf16x8*)(Wl + (mt * 16 + r) * KP2 + ko);
      acc2[mt][0] = __builtin_amdgcn_mfma_f32_16x16x32_bf16(A, B0, acc2[mt][0], 0, 0, 0);
      acc2[mt][1] = __builtin_amdgcn_mfma_f32_16x16x32_bf16(A, B1, acc2[mt][1], 0, 0, 0);
    }
  }
#pragma unroll
  for (int mt = 0; mt < 4; ++mt)
#pragma unroll
    for (int nt = 0; nt < 2; ++nt) {
      f32x4 v = acc2[mt][nt];
      v[0] = fmaxf(v[0], 0.f); v[1] = fmaxf(v[1], 0.f);
      v[2] = fmaxf(v[2], 0.f); v[3] = fmaxf(v[3], 0.f);
      int2 w; w.x = pk(v[0], v[1]); w.y = pk(v[2], v[3]);
      *(int2*)(Xl + (n0 + nt * 16 + r) * KP2 + mt * 16 + g * 4) = w;
    }
  __syncthreads();  // all waves done reading W2 tile

  // ---- layer 3: W3[128][64] x Y2, fused relu + maxpool + store ----
  for (int t = tid; t < 1152; t += 256) ((int4*)Wl)[t] = ((const int4*)w3b)[t];
  __syncthreads();
  f32x4 acc3[8][2];
#pragma unroll
  for (int mt = 0; mt < 8; ++mt) {
    f32x4 bv = *(const f32x4*)(b3 + mt * 16 + g * 4);
    acc3[mt][0] = bv; acc3[mt][1] = bv;
  }
#pragma unroll
  for (int kt = 0; kt < 2; ++kt) {
    const int ko = kt * 32 + g * 8;
    bf16x8 B0 = *(const bf16x8*)(Xl + (n0 + r) * KP2 + ko);
    bf16x8 B1 = *(const bf16x8*)(Xl + (n0 + 16 + r) * KP2 + ko);
#pragma unroll
    for (int mt = 0; mt < 8; ++mt) {
      bf16x8 A = *(const bf16x8*)(Wl + (mt * 16 + r) * KP2 + ko);
      acc3[mt][0] = __builtin_amdgcn_mfma_f32_16x16x32_bf16(A, B0, acc3[mt][0], 0, 0, 0);
      acc3[mt][1] = __builtin_amdgcn_mfma_f32_16x16x32_bf16(A, B1, acc3[mt][1], 0, 0, 0);
    }
  }
#pragma unroll
  for (int mt = 0; mt < 8; ++mt) {
    f32x4 u = acc3[mt][0], v = acc3[mt][1];
    float m0 = fmaxf(fmaxf(u[0], v[0]), 0.0f);
    float m1 = fmaxf(fmaxf(u[1], v[1]), 0.0f);
    float m2 = fmaxf(fmaxf(u[2], v[2]), 0.0f);
    float m3 = fmaxf(fmaxf(u[3], v[3]), 0.0f);
    RED16(m0); RED16(m1); RED16(m2); RED16(m3);
    if (r == 0) {
      float* op = out + ((size_t)b * 128 + mt * 16 + g * 4) * NM + mq;
      op[0] = m0; op[NM] = m1; op[2 * NM] = m2; op[3 * NM] = m3;
    }
  }
}

// ---------- launch ----------

extern "C" void kernel_launch(void* const* d_in, const int* in_sizes, int n_in,
                              void* d_out, int out_size, void* d_ws, size_t ws_size,
                              hipStream_t stream) {
  (void)in_sizes; (void)n_in; (void)out_size; (void)ws_size;
  const float* feat = (const float*)d_in[0];
  const float* loc  = (const float*)d_in[1];
  const float* W1   = (const float*)d_in[2];
  const float* b1   = (const float*)d_in[3];
  const float* W2   = (const float*)d_in[4];
  const float* b2   = (const float*)d_in[5];
  const float* W3   = (const float*)d_in[6];
  const float* b3   = (const float*)d_in[7];
  float* out = (float*)d_out;

  char* ws = (char*)d_ws;
  int*   ws_knn   = (int*)ws;                           // 2 MB
  float* ws_featT = (float*)(ws + 2097152);             // 16.75 MB
  short* ws_w1b   = (short*)(ws + 18874368);            // 64*104 bf16
  short* ws_w2b   = (short*)(ws + 18874368 + 13312);    // 64*72 bf16
  short* ws_w3b   = (short*)(ws + 18874368 + 22528);    // 128*72 bf16

  float* out_setfeat = out;                          // (16,128,1024)
  float* out_setloc  = out + (size_t)NB * 128 * NM;  // (16,3,1024)

  fps_fused<<<dim3(2074), dim3(256), 0, stream>>>(
      loc, out_setloc, feat, ws_featT, W1, W2, W3, ws_w1b, ws_w2b, ws_w3b);
  knn_kernel<<<dim3((NB * NM) / 4), dim3(256), 0, stream>>>(loc, out_setloc, ws_knn);
  mlp_mfma<<<dim3((NB * NM) / 4), dim3(256), 0, stream>>>(
      ws_featT, loc, out_setloc, ws_knn, ws_w1b, ws_w2b, ws_w3b, b1, b2, b3, out_setfeat);
}